// Round 14
// baseline (598.982 us; speedup 1.0000x reference)
//
#include <hip/hip_runtime.h>

// HyperGAT layer, N=16384, E=4096, D=256 on gfx950.
//   xw1 = x@w1 (split-bf16 MFMA, ~fp32 accurate)
//   g_n = satexp(leaky(xw1)@a1), d_n = leaky(xw1)@a22
//   y = g*xw1 quantized to i16 (per-dd global scale), split qh/ql i8 planes
//   C1 = H^T @ [qh|ql]  (i8 MFMA; A-fragments expanded from bit-pack IN REGISTERS)
//   f2 = leaky(C1/den);  G = f2@w2 (split);  c_j = leaky(G)@a21
//   out = leaky((B@G)/rowsum), B[n,j] = Hbit*satexp(c_j+d_n) on the fly,
//   j-split + combine epilogue.
// R3: T14 async-STAGE in gemm_c1_bits + fused_out_split (610.6 -> 598.9 us).
// R8: z=1 fused REGRESSED (625.5): 1 block/CU (8 waves) exposed barrier drains.
// R9: revert + T14 on gemm_xw1/gemm_G: 598.3 us (T14 there = null; kept).
// R11: fused z=4 -> z=2: 590.3 us (-8; 16 waves/CU keep overlap, outP halved).
// R12: gemm_c1_bits scales partials by ddmax and atomicAdds straight into C1
//   (fp32, <=8-way contention); C1 zeroed in quantize_y (grid-stride, runs
//   just before). reduce_C1 kernel + 37.75MB C1p buffer ELIMINATED.
// R13: identical resubmit (R12 never benched — broker timeout).

typedef __attribute__((ext_vector_type(8))) short short8;
typedef __attribute__((ext_vector_type(4))) short short4v;
typedef __attribute__((ext_vector_type(4))) float f32x4;
typedef __attribute__((ext_vector_type(4))) int int4v;
typedef __attribute__((ext_vector_type(4))) unsigned int uint4v;

__device__ __forceinline__ float leakyf(float v) { return v > 0.f ? v : 0.1f * v; }
__device__ __forceinline__ float fastrcp(float x) { return __builtin_amdgcn_rcpf(x); }

__device__ __forceinline__ float satexpf(float t) {
    float u = fminf(fmaxf(t * 0.25f, -30.f), 30.f);
    float p = __expf(u);
    float th = (p - 1.f) * fastrcp(p + 1.f);
    return __expf(8.f * th);
}

__device__ __forceinline__ short f2b(float v) {
    unsigned int x = __float_as_uint(v);
    x += 0x7fffu + ((x >> 16) & 1u);
    return (short)(x >> 16);
}
__device__ __forceinline__ float b2f(short s) {
    return __uint_as_float(((unsigned int)(unsigned short)s) << 16);
}
// 4 H-bits -> 4 i8 bytes (bit-deposit via magic multiply)
__device__ __forceinline__ unsigned int bits4_to_bytes(unsigned int s) {
    return ((s & 0xFu) * 0x00204081u) & 0x01010101u;
}

// ---------------------------------------------------------------- weight transposes (w1,w2) + hi/lo split
__global__ __launch_bounds__(256) void transpose_split2(
        const float* __restrict__ s0, short* __restrict__ dh0, short* __restrict__ dl0,
        const float* __restrict__ s1, short* __restrict__ dh1, short* __restrict__ dl1) {
    const float* src = blockIdx.z ? s1 : s0;
    short* dh = blockIdx.z ? dh1 : dh0;
    short* dl = blockIdx.z ? dl1 : dl0;
    __shared__ float Ts[64][65];
    const int t = threadIdx.x;
    const long r0 = (long)blockIdx.x * 64;
    const long c0 = (long)blockIdx.y * 64;
    {
        const int row = t >> 2, cc = (t & 3) * 16;
        const float* p = src + (r0 + row) * 256 + c0 + cc;
#pragma unroll
        for (int i = 0; i < 4; ++i) {
            f32x4 v = *reinterpret_cast<const f32x4*>(p + i * 4);
#pragma unroll
            for (int k = 0; k < 4; ++k) Ts[row][cc + i * 4 + k] = v[k];
        }
    }
    __syncthreads();
    {
        const int cl = t >> 2, ch = (t & 3) * 16;
        short8 h0, h1, l0, l1;
#pragma unroll
        for (int i = 0; i < 8; ++i) {
            float v = Ts[ch + i][cl];
            short h = f2b(v);
            h0[i] = h; l0[i] = f2b(v - b2f(h));
        }
#pragma unroll
        for (int i = 0; i < 8; ++i) {
            float v = Ts[ch + 8 + i][cl];
            short h = f2b(v);
            h1[i] = h; l1[i] = f2b(v - b2f(h));
        }
        short* qh = dh + (c0 + cl) * 256 + r0 + ch;
        short* ql = dl + (c0 + cl) * 256 + r0 + ch;
        *reinterpret_cast<short8*>(qh) = h0;
        *reinterpret_cast<short8*>(qh + 8) = h1;
        *reinterpret_cast<short8*>(ql) = l0;
        *reinterpret_cast<short8*>(ql + 8) = l1;
    }
}

// ---------------------------------------------------------------- H -> Hbits (n-major) + HbitsT (j-major); block(0,0) zeroes ddmax/cat
__global__ __launch_bounds__(256) void transposeH_pack(
        const float* __restrict__ H, unsigned int* __restrict__ Hbits,
        unsigned int* __restrict__ HbitsT, unsigned int* __restrict__ ddmax,
        float* __restrict__ cat) {
    __shared__ float Ts[64][65];
    const int t = threadIdx.x;
    const long r0 = (long)blockIdx.x * 64;   // n
    const long c0 = (long)blockIdx.y * 64;   // j
    if (blockIdx.x == 0 && blockIdx.y == 0) {   // fold the two memsets
        if (t < 256) ddmax[t] = 0u;
        if (t < 32) ddmax[256 + t] = 0u;
#pragma unroll
        for (int i = 0; i < 16; ++i) cat[t * 16 + i] = 0.f;
    }
    {
        const int row = t >> 2, cc = (t & 3) * 16;
        const float* p = H + (r0 + row) * 4096L + c0 + cc;
#pragma unroll
        for (int i = 0; i < 4; ++i) {
            f32x4 v = *reinterpret_cast<const f32x4*>(p + i * 4);
#pragma unroll
            for (int k = 0; k < 4; ++k) Ts[row][cc + i * 4 + k] = v[k];
        }
    }
    __syncthreads();
    if (t < 128) {           // Hbits: row n, bits over j
        const int nl = t >> 1, w = t & 1;
        unsigned int u = 0;
#pragma unroll
        for (int b = 0; b < 32; ++b)
            u |= (Ts[nl][w * 32 + b] != 0.f ? 1u : 0u) << b;
        Hbits[(r0 + nl) * 128 + (c0 >> 5) + w] = u;
    } else {                 // HbitsT: row j, bits over n
        const int t2 = t - 128;
        const int jl = t2 >> 1, w = t2 & 1;
        unsigned int u = 0;
#pragma unroll
        for (int b = 0; b < 32; ++b)
            u |= (Ts[w * 32 + b][jl] != 0.f ? 1u : 0u) << b;
        HbitsT[(c0 + jl) * 512 + (r0 >> 5) + w] = u;
    }
}

// ---------------------------------------------------------------- xw1 split GEMM (fp32-accurate)
// R9: T14 — A/B tiles for step k+1 loaded into regs under the MFMA cluster.
__global__ __launch_bounds__(256) void gemm_xw1(
        const float* __restrict__ A, const short* __restrict__ Bh,
        const short* __restrict__ Bl, float* __restrict__ C) {
    __shared__ short Ash[128][72];
    __shared__ short Asl[128][72];
    __shared__ short Bsh[64][72];
    __shared__ short Bsl[64][72];
    const int t = threadIdx.x;
    const int wid = t >> 6, lane = t & 63;
    const int wm = wid & 1, wn = wid >> 1;
    const int quad = lane >> 4, l15 = lane & 15;
    const long m0 = (long)blockIdx.x * 128;
    const long n0 = (long)blockIdx.y * 64;
    // fixed per-thread staging descriptors
    int rA[4], cA[4], rB[2], cB[2];
#pragma unroll
    for (int it = 0; it < 4; ++it) {
        const int cid = t + it * 256;
        rA[it] = cid >> 3; cA[it] = (cid & 7) * 8;
    }
#pragma unroll
    for (int it = 0; it < 2; ++it) {
        const int cid = t + it * 256;
        rB[it] = cid >> 3; cB[it] = (cid & 7) * 8;
    }
    f32x4 acc[4][2];
#pragma unroll
    for (int i = 0; i < 4; ++i)
#pragma unroll
        for (int j = 0; j < 2; ++j)
#pragma unroll
            for (int r = 0; r < 4; ++r) acc[i][j][r] = 0.f;

    // prologue: load kb=0 tiles into regs
    f32x4 av0[4], av1[4];
    short8 bvh[2], bvl[2];
#pragma unroll
    for (int it = 0; it < 4; ++it) {
        const float* ap = A + (m0 + rA[it]) * 256 + cA[it];
        av0[it] = *reinterpret_cast<const f32x4*>(ap);
        av1[it] = *reinterpret_cast<const f32x4*>(ap + 4);
    }
#pragma unroll
    for (int it = 0; it < 2; ++it) {
        bvh[it] = *reinterpret_cast<const short8*>(Bh + (n0 + rB[it]) * 256 + cB[it]);
        bvl[it] = *reinterpret_cast<const short8*>(Bl + (n0 + rB[it]) * 256 + cB[it]);
    }

    for (int kb = 0; kb < 256; kb += 64) {
        // convert + write staged tiles
#pragma unroll
        for (int it = 0; it < 4; ++it) {
            short8 hi, lo;
#pragma unroll
            for (int k = 0; k < 4; ++k) {
                short h0 = f2b(av0[it][k]); hi[k] = h0; lo[k] = f2b(av0[it][k] - b2f(h0));
                short h1 = f2b(av1[it][k]); hi[4 + k] = h1; lo[4 + k] = f2b(av1[it][k] - b2f(h1));
            }
            *reinterpret_cast<short8*>(&Ash[rA[it]][cA[it]]) = hi;
            *reinterpret_cast<short8*>(&Asl[rA[it]][cA[it]]) = lo;
        }
#pragma unroll
        for (int it = 0; it < 2; ++it) {
            *reinterpret_cast<short8*>(&Bsh[rB[it]][cB[it]]) = bvh[it];
            *reinterpret_cast<short8*>(&Bsl[rB[it]][cB[it]]) = bvl[it];
        }
        __syncthreads();
        // prefetch next step (flies under the MFMA cluster)
        const bool pf = (kb < 192);
        f32x4 an0[4], an1[4];
        short8 bnh[2], bnl[2];
        if (pf) {
#pragma unroll
            for (int it = 0; it < 4; ++it) {
                const float* ap = A + (m0 + rA[it]) * 256 + kb + 64 + cA[it];
                an0[it] = *reinterpret_cast<const f32x4*>(ap);
                an1[it] = *reinterpret_cast<const f32x4*>(ap + 4);
            }
#pragma unroll
            for (int it = 0; it < 2; ++it) {
                bnh[it] = *reinterpret_cast<const short8*>(Bh + (n0 + rB[it]) * 256 + kb + 64 + cB[it]);
                bnl[it] = *reinterpret_cast<const short8*>(Bl + (n0 + rB[it]) * 256 + kb + 64 + cB[it]);
            }
        }
#pragma unroll
        for (int ks = 0; ks < 2; ++ks) {
            short8 ah[4], al[4], bh[2], bl[2];
#pragma unroll
            for (int i = 0; i < 4; ++i) {
                ah[i] = *reinterpret_cast<const short8*>(&Ash[wm * 64 + i * 16 + l15][ks * 32 + quad * 8]);
                al[i] = *reinterpret_cast<const short8*>(&Asl[wm * 64 + i * 16 + l15][ks * 32 + quad * 8]);
            }
#pragma unroll
            for (int j = 0; j < 2; ++j) {
                bh[j] = *reinterpret_cast<const short8*>(&Bsh[wn * 32 + j * 16 + l15][ks * 32 + quad * 8]);
                bl[j] = *reinterpret_cast<const short8*>(&Bsl[wn * 32 + j * 16 + l15][ks * 32 + quad * 8]);
            }
#pragma unroll
            for (int i = 0; i < 4; ++i)
#pragma unroll
                for (int j = 0; j < 2; ++j) {
                    acc[i][j] = __builtin_amdgcn_mfma_f32_16x16x32_bf16(ah[i], bh[j], acc[i][j], 0, 0, 0);
                    acc[i][j] = __builtin_amdgcn_mfma_f32_16x16x32_bf16(ah[i], bl[j], acc[i][j], 0, 0, 0);
                    acc[i][j] = __builtin_amdgcn_mfma_f32_16x16x32_bf16(al[i], bh[j], acc[i][j], 0, 0, 0);
                }
        }
        __syncthreads();
        if (pf) {
#pragma unroll
            for (int it = 0; it < 4; ++it) { av0[it] = an0[it]; av1[it] = an1[it]; }
#pragma unroll
            for (int it = 0; it < 2; ++it) { bvh[it] = bnh[it]; bvl[it] = bnl[it]; }
        }
    }
#pragma unroll
    for (int i = 0; i < 4; ++i) {
        const long grow = m0 + wm * 64 + i * 16 + quad * 4;
#pragma unroll
        for (int j = 0; j < 2; ++j) {
            const long gcol = n0 + wn * 32 + j * 16 + l15;
#pragma unroll
            for (int r = 0; r < 4; ++r)
                C[(grow + r) * 256 + gcol] = acc[i][j][r];
        }
    }
}

// ---------------------------------------------------------------- node stats: g, dn, per-dd |y| max
__global__ __launch_bounds__(256) void node_stats1(
        const float* __restrict__ xw1, const float* __restrict__ a1,
        const float* __restrict__ a22, float* __restrict__ g_out,
        float* __restrict__ dn, unsigned int* __restrict__ ddmax) {
    __shared__ float Mx[4][260];
    const int t = threadIdx.x;
    const int n0 = blockIdx.x * 64;
    const int r = t >> 2, q = t & 3;
    const long n = n0 + r;
    const float* xp = xw1 + n * 256 + q * 64;
    float vals[64];
    float facc = 0.f, dacc = 0.f;
#pragma unroll
    for (int i = 0; i < 16; ++i) {
        f32x4 v  = *reinterpret_cast<const f32x4*>(xp + i * 4);
        f32x4 b1 = *reinterpret_cast<const f32x4*>(a1 + q * 64 + i * 4);
        f32x4 b2 = *reinterpret_cast<const f32x4*>(a22 + q * 64 + i * 4);
#pragma unroll
        for (int k = 0; k < 4; ++k) {
            float lv = leakyf(v[k]);
            facc += lv * b1[k];
            dacc += lv * b2[k];
            vals[i * 4 + k] = v[k];
        }
    }
    facc += __shfl_xor(facc, 1); facc += __shfl_xor(facc, 2);
    dacc += __shfl_xor(dacc, 1); dacc += __shfl_xor(dacc, 2);
    const float g = satexpf(facc);
    if (q == 0) { dn[n] = dacc; g_out[n] = g; }
    float lm[64];
#pragma unroll
    for (int i = 0; i < 64; ++i) lm[i] = fabsf(vals[i] * g);
#pragma unroll
    for (int m = 4; m < 64; m <<= 1)
#pragma unroll
        for (int i = 0; i < 64; ++i) lm[i] = fmaxf(lm[i], __shfl_xor(lm[i], m));
    float gm = g;
#pragma unroll
    for (int m = 1; m < 64; m <<= 1) gm = fmaxf(gm, __shfl_xor(gm, m));
    const int wv = t >> 6, lane = t & 63;
    if (lane < 4) {
#pragma unroll
        for (int i = 0; i < 64; ++i) Mx[wv][lane * 64 + i] = lm[i];
    }
    if (lane == 0) Mx[wv][256] = gm;
    __syncthreads();
    if (t < 256) {
        float m = fmaxf(fmaxf(Mx[0][t], Mx[1][t]), fmaxf(Mx[2][t], Mx[3][t]));
        atomicMax(&ddmax[t], __float_as_uint(m));
    }
    if (t == 0) {  // index 256 (g); block has only 256 threads
        float m = fmaxf(fmaxf(Mx[0][256], Mx[1][256]), fmaxf(Mx[2][256], Mx[3][256]));
        atomicMax(&ddmax[256], __float_as_uint(m));
    }
}

// ---------------------------------------------------------------- quantize y -> yQ i8 [576,16384]; R12: also zeroes C1 for atomic accum
__global__ __launch_bounds__(256) void quantize_y(
        const float* __restrict__ xw1, const float* __restrict__ g_in,
        const unsigned int* __restrict__ ddmax, char* __restrict__ yQ,
        float* __restrict__ C1z) {
    __shared__ unsigned int Qh[257][16];
    __shared__ unsigned int Ql[257][16];
    const int t = threadIdx.x;
    const int n0 = blockIdx.x * 64;
    // R12: zero C1 (4096*288 = 1,179,648 floats over 65,536 threads = 18 each, coalesced)
    {
        const int gid = blockIdx.x * 256 + t;
#pragma unroll
        for (int k = 0; k < 18; ++k) C1z[gid + k * 65536] = 0.f;
    }
    const int dd0 = (t >> 4) * 16;
    const int w = t & 15;
    const int r4 = w * 4;
    float s[16];
#pragma unroll
    for (int i = 0; i < 16; ++i)
        s[i] = 32512.f / __uint_as_float(ddmax[dd0 + i]);
    const float sg = 32512.f / __uint_as_float(ddmax[256]);
    unsigned int bh[16], bl[16];
#pragma unroll
    for (int i = 0; i < 16; ++i) { bh[i] = 0u; bl[i] = 0u; }
    unsigned int gh = 0u, gl = 0u;
#pragma unroll
    for (int rr = 0; rr < 4; ++rr) {
        const long n = n0 + r4 + rr;
        const float gg = g_in[n];
        const float* xp = xw1 + n * 256 + dd0;
#pragma unroll
        for (int c = 0; c < 4; ++c) {
            f32x4 v = *reinterpret_cast<const f32x4*>(xp + c * 4);
#pragma unroll
            for (int k = 0; k < 4; ++k) {
                const int i = c * 4 + k;
                int qv = __float2int_rn(v[k] * gg * s[i]);
                qv = max(-32639, min(32639, qv));
                const int qh = (qv + 128) >> 8;
                const int ql = qv - (qh << 8);
                bh[i] |= ((unsigned int)(qh & 255)) << (8 * rr);
                bl[i] |= ((unsigned int)(ql & 255)) << (8 * rr);
            }
        }
        if (t < 16) {
            int qv = __float2int_rn(gg * sg);
            qv = max(-32639, min(32639, qv));
            const int qh = (qv + 128) >> 8;
            const int ql = qv - (qh << 8);
            gh |= ((unsigned int)(qh & 255)) << (8 * rr);
            gl |= ((unsigned int)(ql & 255)) << (8 * rr);
        }
    }
#pragma unroll
    for (int i = 0; i < 16; ++i) { Qh[dd0 + i][w] = bh[i]; Ql[dd0 + i][w] = bl[i]; }
    if (t < 16) { Qh[256][t] = gh; Ql[256][t] = gl; }
    __syncthreads();
#pragma unroll
    for (int it = 0; it < 2; ++it) {
        const int dd = it * 256 + t;
        if (dd < 288) {
#pragma unroll
            for (int s2 = 0; s2 < 4; ++s2) {
                uint4v vh, vl;
                if (dd < 257) {
                    vh = *reinterpret_cast<const uint4v*>(&Qh[dd][s2 * 4]);
                    vl = *reinterpret_cast<const uint4v*>(&Ql[dd][s2 * 4]);
                } else {
#pragma unroll
                    for (int k = 0; k < 4; ++k) { vh[k] = 0u; vl[k] = 0u; }
                }
                *reinterpret_cast<uint4v*>(yQ + (long)dd * 16384 + n0 + s2 * 16) = vh;
                *reinterpret_cast<uint4v*>(yQ + (long)(288 + dd) * 16384 + n0 + s2 * 16) = vl;
            }
        }
    }
}

// ---------------------------------------------------------------- C1 GEMM, i8 MFMA, A-fragments expanded IN REGISTERS
// BM=256 (j), BN=48 (dd), BK=128, z=8 (Ktile 2048), grid (16, 6, 8) = 768 blocks.
// R3: B-staging + bit-loads for step k+1 prefetched into regs during MFMA of k.
// R12: partials scaled by ddmax and atomicAdd'ed into C1 (no C1p / reduce_C1).
__global__ __launch_bounds__(256) void gemm_c1_bits(
        const unsigned int* __restrict__ HbitsT, const char* __restrict__ Bb,
        const unsigned int* __restrict__ ddmax, float* __restrict__ C1) {
    __shared__ char Bsh[48][144];   // 6.9 KB
    __shared__ char Bsl[48][144];   // 6.9 KB
    const int t = threadIdx.x;
    const int wid = t >> 6, lane = t & 63;
    const int quad = lane >> 4, l15 = lane & 15;
    const long m0 = (long)blockIdx.x * 256;
    const long n0 = (long)blockIdx.y * 48;
    const long k0 = (long)blockIdx.z * 2048;
    // this lane's 4 A-rows (j indices): m0 + wid*64 + i*16 + l15
    const unsigned int* bp[4];
#pragma unroll
    for (int i = 0; i < 4; ++i)
        bp[i] = HbitsT + (m0 + wid * 64 + i * 16 + l15) * 512 + (k0 >> 5);
    // staging descriptors (fixed per thread; round-6 bugfix kept: explicit compare)
    char* dstp[3];
    long sbase[3];
#pragma unroll
    for (int it = 0; it < 3; ++it) {
        const int cid = t + it * 256;
        const int idx = (cid < 384) ? cid : cid - 384;
        const int row = idx >> 3, seg = (idx & 7) * 16;
        dstp[it] = (cid >= 384) ? &Bsl[row][seg] : &Bsh[row][seg];
        const long srow = (cid >= 384) ? (288 + n0 + row) : (n0 + row);
        sbase[it] = srow * 16384 + k0 + seg;
    }
    int4v acch[4][3], accl[4][3];
#pragma unroll
    for (int i = 0; i < 4; ++i)
#pragma unroll
        for (int j = 0; j < 3; ++j)
#pragma unroll
            for (int r = 0; r < 4; ++r) { acch[i][j][r] = 0; accl[i][j][r] = 0; }

    // prologue: load bit-words + staged B regs for kb=0
    uint4v bv[4], sv[3];
#pragma unroll
    for (int i = 0; i < 4; ++i)
        bv[i] = *reinterpret_cast<const uint4v*>(bp[i]);
#pragma unroll
    for (int it = 0; it < 3; ++it)
        sv[it] = *reinterpret_cast<const uint4v*>(Bb + sbase[it]);

    for (int kb = 0; kb < 2048; kb += 128) {
        // write current staged tile to LDS
#pragma unroll
        for (int it = 0; it < 3; ++it)
            *reinterpret_cast<uint4v*>(dstp[it]) = sv[it];
        __syncthreads();
        // prefetch next step (overlaps the MFMA cluster below)
        const bool pf = (kb < 1920);
        uint4v bvn[4], svn[3];
        if (pf) {
#pragma unroll
            for (int i = 0; i < 4; ++i)
                bvn[i] = *reinterpret_cast<const uint4v*>(bp[i] + ((kb + 128) >> 5));
#pragma unroll
            for (int it = 0; it < 3; ++it)
                svn[it] = *reinterpret_cast<const uint4v*>(Bb + sbase[it] + kb + 128);
        }
#pragma unroll
        for (int ks = 0; ks < 2; ++ks) {
            int4v af[4], bh[3], bl[3];
#pragma unroll
            for (int i = 0; i < 4; ++i) {
                const unsigned int u =
                    bv[i][ks * 2 + (quad >> 1)] >> ((quad & 1) * 16);
                uint4v e;
#pragma unroll
                for (int k = 0; k < 4; ++k) e[k] = bits4_to_bytes(u >> (4 * k));
                af[i] = __builtin_bit_cast(int4v, e);
            }
#pragma unroll
            for (int j = 0; j < 3; ++j) {
                bh[j] = *reinterpret_cast<const int4v*>(&Bsh[j * 16 + l15][ks * 64 + quad * 16]);
                bl[j] = *reinterpret_cast<const int4v*>(&Bsl[j * 16 + l15][ks * 64 + quad * 16]);
            }
#pragma unroll
            for (int i = 0; i < 4; ++i)
#pragma unroll
                for (int j = 0; j < 3; ++j) {
                    acch[i][j] = __builtin_amdgcn_mfma_i32_16x16x64_i8(af[i], bh[j], acch[i][j], 0, 0, 0);
                    accl[i][j] = __builtin_amdgcn_mfma_i32_16x16x64_i8(af[i], bl[j], accl[i][j], 0, 0, 0);
                }
        }
        __syncthreads();
        if (pf) {
#pragma unroll
            for (int i = 0; i < 4; ++i) bv[i] = bvn[i];
#pragma unroll
            for (int it = 0; it < 3; ++it) sv[it] = svn[it];
        }
    }
    // R12 epilogue: scale by ddmax (distributes over the z-sum) and atomically
    // accumulate into C1. <=8-way contention per address (one per z-block).
    float sc[3];
#pragma unroll
    for (int j = 0; j < 3; ++j)
        sc[j] = __uint_as_float(ddmax[n0 + j * 16 + l15]) * (1.f / 32512.f);
#pragma unroll
    for (int i = 0; i < 4; ++i) {
        const long grow = m0 + wid * 64 + i * 16 + quad * 4;
#pragma unroll
        for (int j = 0; j < 3; ++j) {
            const long gcol = n0 + j * 16 + l15;
#pragma unroll
            for (int r = 0; r < 4; ++r)
                atomicAdd(&C1[(grow + r) * 288 + gcol],
                          (256.f * (float)acch[i][j][r] + (float)accl[i][j][r]) * sc[j]);
        }
    }
}

// ---------------------------------------------------------------- G = f2@w2 split (+ GT bf16, c_j)
// R9: T14 — A/B tiles for step k+1 loaded into regs under the MFMA cluster;
// per-row rcp(den) hoisted out of the K-loop (kb-invariant).
__global__ __launch_bounds__(256) void gemm_G(
        const float* __restrict__ C1, const short* __restrict__ w2Th,
        const short* __restrict__ w2Tl, const float* __restrict__ a21,
        short* __restrict__ GT, float* __restrict__ cat) {
    __shared__ short Ash[64][72];
    __shared__ short Asl[64][72];
    __shared__ short Bsh[64][72];
    __shared__ short Bsl[64][72];
    __shared__ float Gs[64][65];
    const int t = threadIdx.x;
    const int wid = t >> 6, lane = t & 63;
    const int wm = wid & 1, wn = wid >> 1;
    const int quad = lane >> 4, l15 = lane & 15;
    const long j0 = (long)blockIdx.x * 64;
    const long d0 = (long)blockIdx.y * 64;
    // fixed per-thread staging descriptors
    int rS[2], cS[2];
#pragma unroll
    for (int it = 0; it < 2; ++it) {
        const int cid = t + it * 256;
        rS[it] = cid >> 3; cS[it] = (cid & 7) * 8;
    }
    f32x4 acc[2][2];
#pragma unroll
    for (int i = 0; i < 2; ++i)
#pragma unroll
        for (int j = 0; j < 2; ++j)
#pragma unroll
            for (int r = 0; r < 4; ++r) acc[i][j][r] = 0.f;

    // prologue: rd (kb-invariant) + kb=0 tiles into regs
    float rdv[2];
    f32x4 av0[2], av1[2];
    short8 bvh[2], bvl[2];
#pragma unroll
    for (int it = 0; it < 2; ++it) {
        rdv[it] = fastrcp(C1[(j0 + rS[it]) * 288 + 256]);
        const float* ap = C1 + (j0 + rS[it]) * 288 + cS[it];
        av0[it] = *reinterpret_cast<const f32x4*>(ap);
        av1[it] = *reinterpret_cast<const f32x4*>(ap + 4);
        bvh[it] = *reinterpret_cast<const short8*>(w2Th + (d0 + rS[it]) * 256 + cS[it]);
        bvl[it] = *reinterpret_cast<const short8*>(w2Tl + (d0 + rS[it]) * 256 + cS[it]);
    }

    for (int kb = 0; kb < 256; kb += 64) {
        // convert + write staged tiles
#pragma unroll
        for (int it = 0; it < 2; ++it) {
            short8 hi, lo;
#pragma unroll
            for (int k = 0; k < 4; ++k) {
                float f0 = leakyf(av0[it][k] * rdv[it]);
                float f1 = leakyf(av1[it][k] * rdv[it]);
                short h0 = f2b(f0); hi[k] = h0; lo[k] = f2b(f0 - b2f(h0));
                short h1 = f2b(f1); hi[4 + k] = h1; lo[4 + k] = f2b(f1 - b2f(h1));
            }
            *reinterpret_cast<short8*>(&Ash[rS[it]][cS[it]]) = hi;
            *reinterpret_cast<short8*>(&Asl[rS[it]][cS[it]]) = lo;
            *reinterpret_cast<short8*>(&Bsh[rS[it]][cS[it]]) = bvh[it];
            *reinterpret_cast<short8*>(&Bsl[rS[it]][cS[it]]) = bvl[it];
        }
        __syncthreads();
        // prefetch next step
        const bool pf = (kb < 192);
        f32x4 an0[2], an1[2];
        short8 bnh[2], bnl[2];
        if (pf) {
#pragma unroll
            for (int it = 0; it < 2; ++it) {
                const float* ap = C1 + (j0 + rS[it]) * 288 + kb + 64 + cS[it];
                an0[it] = *reinterpret_cast<const f32x4*>(ap);
                an1[it] = *reinterpret_cast<const f32x4*>(ap + 4);
                bnh[it] = *reinterpret_cast<const short8*>(w2Th + (d0 + rS[it]) * 256 + kb + 64 + cS[it]);
                bnl[it] = *reinterpret_cast<const short8*>(w2Tl + (d0 + rS[it]) * 256 + kb + 64 + cS[it]);
            }
        }
#pragma unroll
        for (int ks = 0; ks < 2; ++ks) {
            short8 ah[2], al[2], bh[2], bl[2];
#pragma unroll
            for (int i = 0; i < 2; ++i) {
                ah[i] = *reinterpret_cast<const short8*>(&Ash[wm * 32 + i * 16 + l15][ks * 32 + quad * 8]);
                al[i] = *reinterpret_cast<const short8*>(&Asl[wm * 32 + i * 16 + l15][ks * 32 + quad * 8]);
            }
#pragma unroll
            for (int j = 0; j < 2; ++j) {
                bh[j] = *reinterpret_cast<const short8*>(&Bsh[wn * 32 + j * 16 + l15][ks * 32 + quad * 8]);
                bl[j] = *reinterpret_cast<const short8*>(&Bsl[wn * 32 + j * 16 + l15][ks * 32 + quad * 8]);
            }
#pragma unroll
            for (int i = 0; i < 2; ++i)
#pragma unroll
                for (int j = 0; j < 2; ++j) {
                    acc[i][j] = __builtin_amdgcn_mfma_f32_16x16x32_bf16(ah[i], bh[j], acc[i][j], 0, 0, 0);
                    acc[i][j] = __builtin_amdgcn_mfma_f32_16x16x32_bf16(ah[i], bl[j], acc[i][j], 0, 0, 0);
                    acc[i][j] = __builtin_amdgcn_mfma_f32_16x16x32_bf16(al[i], bh[j], acc[i][j], 0, 0, 0);
                }
        }
        __syncthreads();
        if (pf) {
#pragma unroll
            for (int it = 0; it < 2; ++it) {
                av0[it] = an0[it]; av1[it] = an1[it];
                bvh[it] = bnh[it]; bvl[it] = bnl[it];
            }
        }
    }
#pragma unroll
    for (int i = 0; i < 2; ++i)
#pragma unroll
        for (int j = 0; j < 2; ++j)
#pragma unroll
            for (int r = 0; r < 4; ++r)
                Gs[wm * 32 + i * 16 + quad * 4 + r][wn * 32 + j * 16 + l15] = acc[i][j][r];
    __syncthreads();
    {
        const int jl = t >> 2, q = t & 3;
        float cp = 0.f;
#pragma unroll
        for (int i = 0; i < 16; ++i) {
            const int d = q * 16 + i;
            cp += leakyf(Gs[jl][d]) * a21[d0 + d];
        }
        cp += __shfl_xor(cp, 1); cp += __shfl_xor(cp, 2);
        if (q == 0) atomicAdd(&cat[j0 + jl], cp);
    }
    {
        const int dl = t >> 2, q = t & 3;
        short8 pk0, pk1;
#pragma unroll
        for (int i = 0; i < 8; ++i) pk0[i] = f2b(Gs[q * 16 + i][dl]);
#pragma unroll
        for (int i = 0; i < 8; ++i) pk1[i] = f2b(Gs[q * 16 + 8 + i][dl]);
        short* gp = GT + (d0 + dl) * 4096 + j0 + q * 16;
        *reinterpret_cast<short8*>(gp) = pk0;
        *reinterpret_cast<short8*>(gp + 8) = pk1;
    }
}

// ---------------------------------------------------------------- FUSED edge weights + final GEMM, j-split (R11: z=2)
// BM=64, BN=256, BK=64, Ktile=2048 (z=2), 512 threads, grid (256,2) = 512 blocks.
__global__ __launch_bounds__(512, 4) void fused_out_split(
        const unsigned int* __restrict__ Hbits, const float* __restrict__ cat,
        const float* __restrict__ dn, const short* __restrict__ GT,
        float* __restrict__ outP, float* __restrict__ rsP) {
    __shared__ short As[64][72];    // 9.2 KB
    __shared__ short Bs[256][72];   // 36.9 KB
    __shared__ float rsS[64][8];
    const int t = threadIdx.x;
    const int wid = t >> 6, lane = t & 63;
    const int wm = wid >> 2, wn = wid & 3;    // 2 m-groups x 4 n-groups
    const int quad = lane >> 4, l15 = lane & 15;
    const long m0 = (long)blockIdx.x * 64;
    const int z = blockIdx.y;
    const int kbase = z * 2048;
    const int r = t & 63, c8 = t >> 6;        // B-value role: row r, 8-col chunk c8
    const float drow = dn[m0 + r];
    const int bo = (c8 & 3) * 8;

    f32x4 acc[2][4];
#pragma unroll
    for (int i = 0; i < 2; ++i)
#pragma unroll
        for (int j = 0; j < 4; ++j)
#pragma unroll
            for (int x = 0; x < 4; ++x) acc[i][j][x] = 0.f;
    float racc = 0.f;

    short8 gv[4];   // staged GT tile regs
    short8 pkc;     // staged edge-weight bf16 octet
    // prologue: load + compute step 0
    {
        const int kb = kbase;
#pragma unroll
        for (int it = 0; it < 4; ++it) {
            const int cid = t + it * 512;
            const int row = cid >> 3, cc = (cid & 7) * 8;
            gv[it] = *reinterpret_cast<const short8*>(GT + row * 4096 + kb + cc);
        }
        const unsigned int w = Hbits[(m0 + r) * 128 + (kb >> 5) + (c8 >> 2)];
        const f32x4 cv0 = *reinterpret_cast<const f32x4*>(cat + kb + c8 * 8);
        const f32x4 cv1 = *reinterpret_cast<const f32x4*>(cat + kb + c8 * 8 + 4);
#pragma unroll
        for (int k = 0; k < 8; ++k) {
            const float cvk = (k < 4) ? cv0[k & 3] : cv1[k & 3];
            const float s = ((w >> (bo + k)) & 1u) ? satexpf(cvk + drow) : 0.f;
            const short sb = f2b(s);
            pkc[k] = sb;
            racc += b2f(sb);
        }
    }

    for (int kk = 0; kk < 2048; kk += 64) {
        const int kb = kbase + kk;
        // write staged tile for this step
#pragma unroll
        for (int it = 0; it < 4; ++it) {
            const int cid = t + it * 512;
            const int row = cid >> 3, cc = (cid & 7) * 8;
            *reinterpret_cast<short8*>(&Bs[row][cc]) = gv[it];
        }
        *reinterpret_cast<short8*>(&As[r][c8 * 8]) = pkc;
        __syncthreads();

        // prefetch step k+1 (loads fly under the MFMA cluster)
        const bool pf = (kk < 1984);
        unsigned int hw = 0u;
        f32x4 cn0{}, cn1{};
        if (pf) {
            const int kn = kb + 64;
#pragma unroll
            for (int it = 0; it < 4; ++it) {
                const int cid = t + it * 512;
                const int row = cid >> 3, cc = (cid & 7) * 8;
                gv[it] = *reinterpret_cast<const short8*>(GT + row * 4096 + kn + cc);
            }
            hw = Hbits[(m0 + r) * 128 + (kn >> 5) + (c8 >> 2)];
            cn0 = *reinterpret_cast<const f32x4*>(cat + kn + c8 * 8);
            cn1 = *reinterpret_cast<const f32x4*>(cat + kn + c8 * 8 + 4);
        }

#pragma unroll
        for (int ks = 0; ks < 2; ++ks) {
            short8 af[2], bf[4];
#pragma unroll
            for (int i = 0; i < 2; ++i)
                af[i] = *reinterpret_cast<const short8*>(
                        &As[wm * 32 + i * 16 + l15][ks * 32 + quad * 8]);
#pragma unroll
            for (int j = 0; j < 4; ++j)
                bf[j] = *reinterpret_cast<const short8*>(
                        &Bs[wn * 64 + j * 16 + l15][ks * 32 + quad * 8]);
#pragma unroll
            for (int i = 0; i < 2; ++i)
#pragma unroll
                for (int j = 0; j < 4; ++j)
                    acc[i][j] = __builtin_amdgcn_mfma_f32_16x16x32_bf16(
                            af[i], bf[j], acc[i][j], 0, 0, 0);
        }

        // compute next step's edge weights (load results have had MFMA time to land)
        if (pf) {
#pragma unroll
            for (int k = 0; k < 8; ++k) {
                const float cvk = (k < 4) ? cn0[k & 3] : cn1[k & 3];
                const float s = ((hw >> (bo + k)) & 1u) ? satexpf(cvk + drow) : 0.f;
                const short sb = f2b(s);
                pkc[k] = sb;
                racc += b2f(sb);
            }
        }
        __syncthreads();
    }
    rsS[r][c8] = racc;
    __syncthreads();
    if (t < 64) {
        float s = 0.f;
#pragma unroll
        for (int i = 0; i < 8; ++i) s += rsS[t][i];
        rsP[z * 16384 + m0 + t] = s;
    }
    float* op = outP + (long)z * (16384L * 256);
#pragma unroll
    for (int i = 0; i < 2; ++i) {
#pragma unroll
        for (int j = 0; j < 4; ++j) {
            const long gcol = wn * 64 + j * 16 + l15;
#pragma unroll
            for (int x = 0; x < 4; ++x) {
                const long grow = m0 + wm * 32 + i * 16 + quad * 4 + x;
                op[grow * 256 + gcol] = acc[i][j][x];
            }
        }
    }
}

// ---------------------------------------------------------------- combine: out = leaky(sum_z outP / sum_z rsP)  (z=2)
__global__ __launch_bounds__(256) void combine_out(
        const float* __restrict__ outP, const float* __restrict__ rsP,
        float* __restrict__ out) {
    const long i = ((long)blockIdx.x * 256 + threadIdx.x) * 4;  // grid 4096
    const long n = i >> 8;
    f32x4 s = *reinterpret_cast<const f32x4*>(outP + i);
    {
        f32x4 v = *reinterpret_cast<const f32x4*>(outP + (16384L * 256) + i);
#pragma unroll
        for (int k = 0; k < 4; ++k) s[k] += v[k];
    }
    const float rinv = fastrcp(rsP[n] + rsP[16384 + n]);
    f32x4 o;
#pragma unroll
    for (int k = 0; k < 4; ++k) o[k] = leakyf(s[k] * rinv);
    *reinterpret_cast<f32x4*>(out + i) = o;
}

// ---------------------------------------------------------------- launch
extern "C" void kernel_launch(void* const* d_in, const int* in_sizes, int n_in,
                              void* d_out, int out_size, void* d_ws, size_t ws_size,
                              hipStream_t stream) {
    const float* x   = (const float*)d_in[0];
    const float* H   = (const float*)d_in[1];
    const float* w1  = (const float*)d_in[2];
    const float* w2  = (const float*)d_in[3];
    const float* a1  = (const float*)d_in[4];
    const float* a21 = (const float*)d_in[5];
    const float* a22 = (const float*)d_in[6];
    float* out = (float*)d_out;
    char* ws = (char*)d_ws;

    float* xw1   = (float*)(ws + 0);                      // 16.8MB
    char*  yQ    = (char*)(ws + 67108864);                // [576,16384] i8 (9.44MB)
    float* dn    = (float*)(ws + 76546048);               // [16384]
    float* g     = (float*)(ws + 76611584);               // [16384]
    unsigned int* ddmax = (unsigned int*)(ws + 76677120); // [288]
    short* w1Th  = (short*)(ws + 76681216);
    short* w1Tl  = (short*)(ws + 76812288);
    short* w2Th  = (short*)(ws + 76943360);
    short* w2Tl  = (short*)(ws + 77074432);
    float* C1    = (float*)(ws + 77205504);               // [4096,288]
    short* GT    = (short*)(ws + 81924096);               // [256,4096] bf16
    float* cat   = (float*)(ws + 84021248);               // [4096]
    unsigned int* Hbits  = (unsigned int*)(ws + 84037632);// [16384,128] (8MB)
    unsigned int* HbitsT = (unsigned int*)(ws + 92426240);// [4096,512]  (8MB)
    float* outP  = (float*)(ws + 134217728);              // [2][16384,256] (33.6MB)
    float* rsP   = (float*)(ws + 201326592);              // [2][16384]

    transpose_split2<<<dim3(4, 4, 2), 256, 0, stream>>>(
            w1, w1Th, w1Tl, w2, w2Th, w2Tl);
    transposeH_pack<<<dim3(256, 64), 256, 0, stream>>>(H, Hbits, HbitsT, ddmax, cat);

    gemm_xw1<<<dim3(128, 4), 256, 0, stream>>>(x, w1Th, w1Tl, xw1);
    node_stats1<<<dim3(256), 256, 0, stream>>>(xw1, a1, a22, g, dn, ddmax);
    quantize_y<<<dim3(256), 256, 0, stream>>>(xw1, g, ddmax, yQ, C1);

    gemm_c1_bits<<<dim3(16, 6, 8), 256, 0, stream>>>(HbitsT, yQ, ddmax, C1);

    gemm_G<<<dim3(64, 4), 256, 0, stream>>>(C1, w2Th, w2Tl, a21, GT, cat);

    fused_out_split<<<dim3(256, 2), 512, 0, stream>>>(Hbits, cat, dn, GT, outP, rsP);
    combine_out<<<dim3(4096), 256, 0, stream>>>(outP, rsP, out);
}

// Round 16
// 591.458 us; speedup vs baseline: 1.0127x; 1.0127x over previous
//
#include <hip/hip_runtime.h>

// HyperGAT layer, N=16384, E=4096, D=256 on gfx950.
//   xw1 = x@w1 (split-bf16 MFMA, ~fp32 accurate)
//   g_n = satexp(leaky(xw1)@a1), d_n = leaky(xw1)@a22
//   y = g*xw1 quantized to i16 (per-dd global scale), split qh/ql i8 planes
//   C1 = H^T @ [qh|ql]  (i8 MFMA; A-fragments expanded from bit-pack IN REGISTERS)
//   f2 = leaky(C1/den);  G = f2@w2 (split);  c_j = leaky(G)@a21
//   out = leaky((B@G)/rowsum), B[n,j] = Hbit*satexp(c_j+d_n) on the fly,
//   j-split + combine epilogue.
// R3: T14 async-STAGE in gemm_c1_bits + fused_out_split (610.6 -> 598.9 us).
// R8: z=1 fused REGRESSED (625.5): 1 block/CU (8 waves) exposed barrier drains.
// R9: revert + T14 on gemm_xw1/gemm_G: 598.3 us (T14 there = null; kept).
// R11: fused z=4 -> z=2: 590.3 us (-8; 16 waves/CU keep overlap, outP halved).
// R12: atomic-C1 (kill reduce_C1) REGRESSED (599.0): C1p round-trip was
//   L3-absorbed; 9.4M scattered atomics + zero-fill cost more than saved.
// R14/R15: REVERT to R11 (590.3 us verified best). Lesson: L3-resident
//   round-trips are near-free; only HBM-visible traffic + launches count.

typedef __attribute__((ext_vector_type(8))) short short8;
typedef __attribute__((ext_vector_type(4))) short short4v;
typedef __attribute__((ext_vector_type(4))) float f32x4;
typedef __attribute__((ext_vector_type(4))) int int4v;
typedef __attribute__((ext_vector_type(4))) unsigned int uint4v;

__device__ __forceinline__ float leakyf(float v) { return v > 0.f ? v : 0.1f * v; }
__device__ __forceinline__ float fastrcp(float x) { return __builtin_amdgcn_rcpf(x); }

__device__ __forceinline__ float satexpf(float t) {
    float u = fminf(fmaxf(t * 0.25f, -30.f), 30.f);
    float p = __expf(u);
    float th = (p - 1.f) * fastrcp(p + 1.f);
    return __expf(8.f * th);
}

__device__ __forceinline__ short f2b(float v) {
    unsigned int x = __float_as_uint(v);
    x += 0x7fffu + ((x >> 16) & 1u);
    return (short)(x >> 16);
}
__device__ __forceinline__ float b2f(short s) {
    return __uint_as_float(((unsigned int)(unsigned short)s) << 16);
}
// 4 H-bits -> 4 i8 bytes (bit-deposit via magic multiply)
__device__ __forceinline__ unsigned int bits4_to_bytes(unsigned int s) {
    return ((s & 0xFu) * 0x00204081u) & 0x01010101u;
}

// ---------------------------------------------------------------- weight transposes (w1,w2) + hi/lo split
__global__ __launch_bounds__(256) void transpose_split2(
        const float* __restrict__ s0, short* __restrict__ dh0, short* __restrict__ dl0,
        const float* __restrict__ s1, short* __restrict__ dh1, short* __restrict__ dl1) {
    const float* src = blockIdx.z ? s1 : s0;
    short* dh = blockIdx.z ? dh1 : dh0;
    short* dl = blockIdx.z ? dl1 : dl0;
    __shared__ float Ts[64][65];
    const int t = threadIdx.x;
    const long r0 = (long)blockIdx.x * 64;
    const long c0 = (long)blockIdx.y * 64;
    {
        const int row = t >> 2, cc = (t & 3) * 16;
        const float* p = src + (r0 + row) * 256 + c0 + cc;
#pragma unroll
        for (int i = 0; i < 4; ++i) {
            f32x4 v = *reinterpret_cast<const f32x4*>(p + i * 4);
#pragma unroll
            for (int k = 0; k < 4; ++k) Ts[row][cc + i * 4 + k] = v[k];
        }
    }
    __syncthreads();
    {
        const int cl = t >> 2, ch = (t & 3) * 16;
        short8 h0, h1, l0, l1;
#pragma unroll
        for (int i = 0; i < 8; ++i) {
            float v = Ts[ch + i][cl];
            short h = f2b(v);
            h0[i] = h; l0[i] = f2b(v - b2f(h));
        }
#pragma unroll
        for (int i = 0; i < 8; ++i) {
            float v = Ts[ch + 8 + i][cl];
            short h = f2b(v);
            h1[i] = h; l1[i] = f2b(v - b2f(h));
        }
        short* qh = dh + (c0 + cl) * 256 + r0 + ch;
        short* ql = dl + (c0 + cl) * 256 + r0 + ch;
        *reinterpret_cast<short8*>(qh) = h0;
        *reinterpret_cast<short8*>(qh + 8) = h1;
        *reinterpret_cast<short8*>(ql) = l0;
        *reinterpret_cast<short8*>(ql + 8) = l1;
    }
}

// ---------------------------------------------------------------- H -> Hbits (n-major) + HbitsT (j-major); block(0,0) zeroes ddmax/cat
__global__ __launch_bounds__(256) void transposeH_pack(
        const float* __restrict__ H, unsigned int* __restrict__ Hbits,
        unsigned int* __restrict__ HbitsT, unsigned int* __restrict__ ddmax,
        float* __restrict__ cat) {
    __shared__ float Ts[64][65];
    const int t = threadIdx.x;
    const long r0 = (long)blockIdx.x * 64;   // n
    const long c0 = (long)blockIdx.y * 64;   // j
    if (blockIdx.x == 0 && blockIdx.y == 0) {   // fold the two memsets
        if (t < 256) ddmax[t] = 0u;
        if (t < 32) ddmax[256 + t] = 0u;
#pragma unroll
        for (int i = 0; i < 16; ++i) cat[t * 16 + i] = 0.f;
    }
    {
        const int row = t >> 2, cc = (t & 3) * 16;
        const float* p = H + (r0 + row) * 4096L + c0 + cc;
#pragma unroll
        for (int i = 0; i < 4; ++i) {
            f32x4 v = *reinterpret_cast<const f32x4*>(p + i * 4);
#pragma unroll
            for (int k = 0; k < 4; ++k) Ts[row][cc + i * 4 + k] = v[k];
        }
    }
    __syncthreads();
    if (t < 128) {           // Hbits: row n, bits over j
        const int nl = t >> 1, w = t & 1;
        unsigned int u = 0;
#pragma unroll
        for (int b = 0; b < 32; ++b)
            u |= (Ts[nl][w * 32 + b] != 0.f ? 1u : 0u) << b;
        Hbits[(r0 + nl) * 128 + (c0 >> 5) + w] = u;
    } else {                 // HbitsT: row j, bits over n
        const int t2 = t - 128;
        const int jl = t2 >> 1, w = t2 & 1;
        unsigned int u = 0;
#pragma unroll
        for (int b = 0; b < 32; ++b)
            u |= (Ts[w * 32 + b][jl] != 0.f ? 1u : 0u) << b;
        HbitsT[(c0 + jl) * 512 + (r0 >> 5) + w] = u;
    }
}

// ---------------------------------------------------------------- xw1 split GEMM (fp32-accurate)
// R9: T14 — A/B tiles for step k+1 loaded into regs under the MFMA cluster.
__global__ __launch_bounds__(256) void gemm_xw1(
        const float* __restrict__ A, const short* __restrict__ Bh,
        const short* __restrict__ Bl, float* __restrict__ C) {
    __shared__ short Ash[128][72];
    __shared__ short Asl[128][72];
    __shared__ short Bsh[64][72];
    __shared__ short Bsl[64][72];
    const int t = threadIdx.x;
    const int wid = t >> 6, lane = t & 63;
    const int wm = wid & 1, wn = wid >> 1;
    const int quad = lane >> 4, l15 = lane & 15;
    const long m0 = (long)blockIdx.x * 128;
    const long n0 = (long)blockIdx.y * 64;
    // fixed per-thread staging descriptors
    int rA[4], cA[4], rB[2], cB[2];
#pragma unroll
    for (int it = 0; it < 4; ++it) {
        const int cid = t + it * 256;
        rA[it] = cid >> 3; cA[it] = (cid & 7) * 8;
    }
#pragma unroll
    for (int it = 0; it < 2; ++it) {
        const int cid = t + it * 256;
        rB[it] = cid >> 3; cB[it] = (cid & 7) * 8;
    }
    f32x4 acc[4][2];
#pragma unroll
    for (int i = 0; i < 4; ++i)
#pragma unroll
        for (int j = 0; j < 2; ++j)
#pragma unroll
            for (int r = 0; r < 4; ++r) acc[i][j][r] = 0.f;

    // prologue: load kb=0 tiles into regs
    f32x4 av0[4], av1[4];
    short8 bvh[2], bvl[2];
#pragma unroll
    for (int it = 0; it < 4; ++it) {
        const float* ap = A + (m0 + rA[it]) * 256 + cA[it];
        av0[it] = *reinterpret_cast<const f32x4*>(ap);
        av1[it] = *reinterpret_cast<const f32x4*>(ap + 4);
    }
#pragma unroll
    for (int it = 0; it < 2; ++it) {
        bvh[it] = *reinterpret_cast<const short8*>(Bh + (n0 + rB[it]) * 256 + cB[it]);
        bvl[it] = *reinterpret_cast<const short8*>(Bl + (n0 + rB[it]) * 256 + cB[it]);
    }

    for (int kb = 0; kb < 256; kb += 64) {
        // convert + write staged tiles
#pragma unroll
        for (int it = 0; it < 4; ++it) {
            short8 hi, lo;
#pragma unroll
            for (int k = 0; k < 4; ++k) {
                short h0 = f2b(av0[it][k]); hi[k] = h0; lo[k] = f2b(av0[it][k] - b2f(h0));
                short h1 = f2b(av1[it][k]); hi[4 + k] = h1; lo[4 + k] = f2b(av1[it][k] - b2f(h1));
            }
            *reinterpret_cast<short8*>(&Ash[rA[it]][cA[it]]) = hi;
            *reinterpret_cast<short8*>(&Asl[rA[it]][cA[it]]) = lo;
        }
#pragma unroll
        for (int it = 0; it < 2; ++it) {
            *reinterpret_cast<short8*>(&Bsh[rB[it]][cB[it]]) = bvh[it];
            *reinterpret_cast<short8*>(&Bsl[rB[it]][cB[it]]) = bvl[it];
        }
        __syncthreads();
        // prefetch next step (flies under the MFMA cluster)
        const bool pf = (kb < 192);
        f32x4 an0[4], an1[4];
        short8 bnh[2], bnl[2];
        if (pf) {
#pragma unroll
            for (int it = 0; it < 4; ++it) {
                const float* ap = A + (m0 + rA[it]) * 256 + kb + 64 + cA[it];
                an0[it] = *reinterpret_cast<const f32x4*>(ap);
                an1[it] = *reinterpret_cast<const f32x4*>(ap + 4);
            }
#pragma unroll
            for (int it = 0; it < 2; ++it) {
                bnh[it] = *reinterpret_cast<const short8*>(Bh + (n0 + rB[it]) * 256 + kb + 64 + cB[it]);
                bnl[it] = *reinterpret_cast<const short8*>(Bl + (n0 + rB[it]) * 256 + kb + 64 + cB[it]);
            }
        }
#pragma unroll
        for (int ks = 0; ks < 2; ++ks) {
            short8 ah[4], al[4], bh[2], bl[2];
#pragma unroll
            for (int i = 0; i < 4; ++i) {
                ah[i] = *reinterpret_cast<const short8*>(&Ash[wm * 64 + i * 16 + l15][ks * 32 + quad * 8]);
                al[i] = *reinterpret_cast<const short8*>(&Asl[wm * 64 + i * 16 + l15][ks * 32 + quad * 8]);
            }
#pragma unroll
            for (int j = 0; j < 2; ++j) {
                bh[j] = *reinterpret_cast<const short8*>(&Bsh[wn * 32 + j * 16 + l15][ks * 32 + quad * 8]);
                bl[j] = *reinterpret_cast<const short8*>(&Bsl[wn * 32 + j * 16 + l15][ks * 32 + quad * 8]);
            }
#pragma unroll
            for (int i = 0; i < 4; ++i)
#pragma unroll
                for (int j = 0; j < 2; ++j) {
                    acc[i][j] = __builtin_amdgcn_mfma_f32_16x16x32_bf16(ah[i], bh[j], acc[i][j], 0, 0, 0);
                    acc[i][j] = __builtin_amdgcn_mfma_f32_16x16x32_bf16(ah[i], bl[j], acc[i][j], 0, 0, 0);
                    acc[i][j] = __builtin_amdgcn_mfma_f32_16x16x32_bf16(al[i], bh[j], acc[i][j], 0, 0, 0);
                }
        }
        __syncthreads();
        if (pf) {
#pragma unroll
            for (int it = 0; it < 4; ++it) { av0[it] = an0[it]; av1[it] = an1[it]; }
#pragma unroll
            for (int it = 0; it < 2; ++it) { bvh[it] = bnh[it]; bvl[it] = bnl[it]; }
        }
    }
#pragma unroll
    for (int i = 0; i < 4; ++i) {
        const long grow = m0 + wm * 64 + i * 16 + quad * 4;
#pragma unroll
        for (int j = 0; j < 2; ++j) {
            const long gcol = n0 + wn * 32 + j * 16 + l15;
#pragma unroll
            for (int r = 0; r < 4; ++r)
                C[(grow + r) * 256 + gcol] = acc[i][j][r];
        }
    }
}

// ---------------------------------------------------------------- node stats: g, dn, per-dd |y| max
__global__ __launch_bounds__(256) void node_stats1(
        const float* __restrict__ xw1, const float* __restrict__ a1,
        const float* __restrict__ a22, float* __restrict__ g_out,
        float* __restrict__ dn, unsigned int* __restrict__ ddmax) {
    __shared__ float Mx[4][260];
    const int t = threadIdx.x;
    const int n0 = blockIdx.x * 64;
    const int r = t >> 2, q = t & 3;
    const long n = n0 + r;
    const float* xp = xw1 + n * 256 + q * 64;
    float vals[64];
    float facc = 0.f, dacc = 0.f;
#pragma unroll
    for (int i = 0; i < 16; ++i) {
        f32x4 v  = *reinterpret_cast<const f32x4*>(xp + i * 4);
        f32x4 b1 = *reinterpret_cast<const f32x4*>(a1 + q * 64 + i * 4);
        f32x4 b2 = *reinterpret_cast<const f32x4*>(a22 + q * 64 + i * 4);
#pragma unroll
        for (int k = 0; k < 4; ++k) {
            float lv = leakyf(v[k]);
            facc += lv * b1[k];
            dacc += lv * b2[k];
            vals[i * 4 + k] = v[k];
        }
    }
    facc += __shfl_xor(facc, 1); facc += __shfl_xor(facc, 2);
    dacc += __shfl_xor(dacc, 1); dacc += __shfl_xor(dacc, 2);
    const float g = satexpf(facc);
    if (q == 0) { dn[n] = dacc; g_out[n] = g; }
    float lm[64];
#pragma unroll
    for (int i = 0; i < 64; ++i) lm[i] = fabsf(vals[i] * g);
#pragma unroll
    for (int m = 4; m < 64; m <<= 1)
#pragma unroll
        for (int i = 0; i < 64; ++i) lm[i] = fmaxf(lm[i], __shfl_xor(lm[i], m));
    float gm = g;
#pragma unroll
    for (int m = 1; m < 64; m <<= 1) gm = fmaxf(gm, __shfl_xor(gm, m));
    const int wv = t >> 6, lane = t & 63;
    if (lane < 4) {
#pragma unroll
        for (int i = 0; i < 64; ++i) Mx[wv][lane * 64 + i] = lm[i];
    }
    if (lane == 0) Mx[wv][256] = gm;
    __syncthreads();
    if (t < 256) {
        float m = fmaxf(fmaxf(Mx[0][t], Mx[1][t]), fmaxf(Mx[2][t], Mx[3][t]));
        atomicMax(&ddmax[t], __float_as_uint(m));
    }
    if (t == 0) {  // index 256 (g); block has only 256 threads
        float m = fmaxf(fmaxf(Mx[0][256], Mx[1][256]), fmaxf(Mx[2][256], Mx[3][256]));
        atomicMax(&ddmax[256], __float_as_uint(m));
    }
}

// ---------------------------------------------------------------- quantize y -> yQ i8 [576,16384]
__global__ __launch_bounds__(256) void quantize_y(
        const float* __restrict__ xw1, const float* __restrict__ g_in,
        const unsigned int* __restrict__ ddmax, char* __restrict__ yQ) {
    __shared__ unsigned int Qh[257][16];
    __shared__ unsigned int Ql[257][16];
    const int t = threadIdx.x;
    const int n0 = blockIdx.x * 64;
    const int dd0 = (t >> 4) * 16;
    const int w = t & 15;
    const int r4 = w * 4;
    float s[16];
#pragma unroll
    for (int i = 0; i < 16; ++i)
        s[i] = 32512.f / __uint_as_float(ddmax[dd0 + i]);
    const float sg = 32512.f / __uint_as_float(ddmax[256]);
    unsigned int bh[16], bl[16];
#pragma unroll
    for (int i = 0; i < 16; ++i) { bh[i] = 0u; bl[i] = 0u; }
    unsigned int gh = 0u, gl = 0u;
#pragma unroll
    for (int rr = 0; rr < 4; ++rr) {
        const long n = n0 + r4 + rr;
        const float gg = g_in[n];
        const float* xp = xw1 + n * 256 + dd0;
#pragma unroll
        for (int c = 0; c < 4; ++c) {
            f32x4 v = *reinterpret_cast<const f32x4*>(xp + c * 4);
#pragma unroll
            for (int k = 0; k < 4; ++k) {
                const int i = c * 4 + k;
                int qv = __float2int_rn(v[k] * gg * s[i]);
                qv = max(-32639, min(32639, qv));
                const int qh = (qv + 128) >> 8;
                const int ql = qv - (qh << 8);
                bh[i] |= ((unsigned int)(qh & 255)) << (8 * rr);
                bl[i] |= ((unsigned int)(ql & 255)) << (8 * rr);
            }
        }
        if (t < 16) {
            int qv = __float2int_rn(gg * sg);
            qv = max(-32639, min(32639, qv));
            const int qh = (qv + 128) >> 8;
            const int ql = qv - (qh << 8);
            gh |= ((unsigned int)(qh & 255)) << (8 * rr);
            gl |= ((unsigned int)(ql & 255)) << (8 * rr);
        }
    }
#pragma unroll
    for (int i = 0; i < 16; ++i) { Qh[dd0 + i][w] = bh[i]; Ql[dd0 + i][w] = bl[i]; }
    if (t < 16) { Qh[256][t] = gh; Ql[256][t] = gl; }
    __syncthreads();
#pragma unroll
    for (int it = 0; it < 2; ++it) {
        const int dd = it * 256 + t;
        if (dd < 288) {
#pragma unroll
            for (int s2 = 0; s2 < 4; ++s2) {
                uint4v vh, vl;
                if (dd < 257) {
                    vh = *reinterpret_cast<const uint4v*>(&Qh[dd][s2 * 4]);
                    vl = *reinterpret_cast<const uint4v*>(&Ql[dd][s2 * 4]);
                } else {
#pragma unroll
                    for (int k = 0; k < 4; ++k) { vh[k] = 0u; vl[k] = 0u; }
                }
                *reinterpret_cast<uint4v*>(yQ + (long)dd * 16384 + n0 + s2 * 16) = vh;
                *reinterpret_cast<uint4v*>(yQ + (long)(288 + dd) * 16384 + n0 + s2 * 16) = vl;
            }
        }
    }
}

// ---------------------------------------------------------------- C1 GEMM, i8 MFMA, A-fragments expanded IN REGISTERS
// BM=256 (j), BN=48 (dd), BK=128, z=8 (Ktile 2048), grid (16, 6, 8) = 768 blocks.
// R3: B-staging + bit-loads for step k+1 prefetched into regs during MFMA of k.
__global__ __launch_bounds__(256) void gemm_c1_bits(
        const unsigned int* __restrict__ HbitsT, const char* __restrict__ Bb,
        float* __restrict__ Cp) {
    __shared__ char Bsh[48][144];   // 6.9 KB
    __shared__ char Bsl[48][144];   // 6.9 KB
    const int t = threadIdx.x;
    const int wid = t >> 6, lane = t & 63;
    const int quad = lane >> 4, l15 = lane & 15;
    const long m0 = (long)blockIdx.x * 256;
    const long n0 = (long)blockIdx.y * 48;
    const long k0 = (long)blockIdx.z * 2048;
    float* Cz = Cp + (long)blockIdx.z * (4096L * 288);
    // this lane's 4 A-rows (j indices): m0 + wid*64 + i*16 + l15
    const unsigned int* bp[4];
#pragma unroll
    for (int i = 0; i < 4; ++i)
        bp[i] = HbitsT + (m0 + wid * 64 + i * 16 + l15) * 512 + (k0 >> 5);
    // staging descriptors (fixed per thread; round-6 bugfix kept: explicit compare)
    char* dstp[3];
    long sbase[3];
#pragma unroll
    for (int it = 0; it < 3; ++it) {
        const int cid = t + it * 256;
        const int idx = (cid < 384) ? cid : cid - 384;
        const int row = idx >> 3, seg = (idx & 7) * 16;
        dstp[it] = (cid >= 384) ? &Bsl[row][seg] : &Bsh[row][seg];
        const long srow = (cid >= 384) ? (288 + n0 + row) : (n0 + row);
        sbase[it] = srow * 16384 + k0 + seg;
    }
    int4v acch[4][3], accl[4][3];
#pragma unroll
    for (int i = 0; i < 4; ++i)
#pragma unroll
        for (int j = 0; j < 3; ++j)
#pragma unroll
            for (int r = 0; r < 4; ++r) { acch[i][j][r] = 0; accl[i][j][r] = 0; }

    // prologue: load bit-words + staged B regs for kb=0
    uint4v bv[4], sv[3];
#pragma unroll
    for (int i = 0; i < 4; ++i)
        bv[i] = *reinterpret_cast<const uint4v*>(bp[i]);
#pragma unroll
    for (int it = 0; it < 3; ++it)
        sv[it] = *reinterpret_cast<const uint4v*>(Bb + sbase[it]);

    for (int kb = 0; kb < 2048; kb += 128) {
        // write current staged tile to LDS
#pragma unroll
        for (int it = 0; it < 3; ++it)
            *reinterpret_cast<uint4v*>(dstp[it]) = sv[it];
        __syncthreads();
        // prefetch next step (overlaps the MFMA cluster below)
        const bool pf = (kb < 1920);
        uint4v bvn[4], svn[3];
        if (pf) {
#pragma unroll
            for (int i = 0; i < 4; ++i)
                bvn[i] = *reinterpret_cast<const uint4v*>(bp[i] + ((kb + 128) >> 5));
#pragma unroll
            for (int it = 0; it < 3; ++it)
                svn[it] = *reinterpret_cast<const uint4v*>(Bb + sbase[it] + kb + 128);
        }
#pragma unroll
        for (int ks = 0; ks < 2; ++ks) {
            int4v af[4], bh[3], bl[3];
#pragma unroll
            for (int i = 0; i < 4; ++i) {
                const unsigned int u =
                    bv[i][ks * 2 + (quad >> 1)] >> ((quad & 1) * 16);
                uint4v e;
#pragma unroll
                for (int k = 0; k < 4; ++k) e[k] = bits4_to_bytes(u >> (4 * k));
                af[i] = __builtin_bit_cast(int4v, e);
            }
#pragma unroll
            for (int j = 0; j < 3; ++j) {
                bh[j] = *reinterpret_cast<const int4v*>(&Bsh[j * 16 + l15][ks * 64 + quad * 16]);
                bl[j] = *reinterpret_cast<const int4v*>(&Bsl[j * 16 + l15][ks * 64 + quad * 16]);
            }
#pragma unroll
            for (int i = 0; i < 4; ++i)
#pragma unroll
                for (int j = 0; j < 3; ++j) {
                    acch[i][j] = __builtin_amdgcn_mfma_i32_16x16x64_i8(af[i], bh[j], acch[i][j], 0, 0, 0);
                    accl[i][j] = __builtin_amdgcn_mfma_i32_16x16x64_i8(af[i], bl[j], accl[i][j], 0, 0, 0);
                }
        }
        __syncthreads();
        if (pf) {
#pragma unroll
            for (int i = 0; i < 4; ++i) bv[i] = bvn[i];
#pragma unroll
            for (int it = 0; it < 3; ++it) sv[it] = svn[it];
        }
    }
#pragma unroll
    for (int i = 0; i < 4; ++i) {
        const long grow = m0 + wid * 64 + i * 16 + quad * 4;
#pragma unroll
        for (int j = 0; j < 3; ++j) {
            const long gcol = n0 + j * 16 + l15;
#pragma unroll
            for (int r = 0; r < 4; ++r)
                Cz[(grow + r) * 288 + gcol] =
                    256.f * (float)acch[i][j][r] + (float)accl[i][j][r];
        }
    }
}

// ---------------------------------------------------------------- reduce split-K partials + reconstruct scale
__global__ __launch_bounds__(256) void reduce_C1(
        const float* __restrict__ C1p, const unsigned int* __restrict__ ddmax,
        float* __restrict__ C1) {
    const int i = blockIdx.x * 256 + threadIdx.x;   // < 4096*288
    const int dd = i % 288;
    float s = 0.f;
#pragma unroll
    for (int z = 0; z < 8; ++z) s += C1p[(long)z * 4096 * 288 + i];
    C1[i] = s * (__uint_as_float(ddmax[dd]) * (1.f / 32512.f));
}

// ---------------------------------------------------------------- G = f2@w2 split (+ GT bf16, c_j)
// R9: T14 — A/B tiles for step k+1 loaded into regs under the MFMA cluster;
// per-row rcp(den) hoisted out of the K-loop (kb-invariant).
__global__ __launch_bounds__(256) void gemm_G(
        const float* __restrict__ C1, const short* __restrict__ w2Th,
        const short* __restrict__ w2Tl, const float* __restrict__ a21,
        short* __restrict__ GT, float* __restrict__ cat) {
    __shared__ short Ash[64][72];
    __shared__ short Asl[64][72];
    __shared__ short Bsh[64][72];
    __shared__ short Bsl[64][72];
    __shared__ float Gs[64][65];
    const int t = threadIdx.x;
    const int wid = t >> 6, lane = t & 63;
    const int wm = wid & 1, wn = wid >> 1;
    const int quad = lane >> 4, l15 = lane & 15;
    const long j0 = (long)blockIdx.x * 64;
    const long d0 = (long)blockIdx.y * 64;
    // fixed per-thread staging descriptors
    int rS[2], cS[2];
#pragma unroll
    for (int it = 0; it < 2; ++it) {
        const int cid = t + it * 256;
        rS[it] = cid >> 3; cS[it] = (cid & 7) * 8;
    }
    f32x4 acc[2][2];
#pragma unroll
    for (int i = 0; i < 2; ++i)
#pragma unroll
        for (int j = 0; j < 2; ++j)
#pragma unroll
            for (int r = 0; r < 4; ++r) acc[i][j][r] = 0.f;

    // prologue: rd (kb-invariant) + kb=0 tiles into regs
    float rdv[2];
    f32x4 av0[2], av1[2];
    short8 bvh[2], bvl[2];
#pragma unroll
    for (int it = 0; it < 2; ++it) {
        rdv[it] = fastrcp(C1[(j0 + rS[it]) * 288 + 256]);
        const float* ap = C1 + (j0 + rS[it]) * 288 + cS[it];
        av0[it] = *reinterpret_cast<const f32x4*>(ap);
        av1[it] = *reinterpret_cast<const f32x4*>(ap + 4);
        bvh[it] = *reinterpret_cast<const short8*>(w2Th + (d0 + rS[it]) * 256 + cS[it]);
        bvl[it] = *reinterpret_cast<const short8*>(w2Tl + (d0 + rS[it]) * 256 + cS[it]);
    }

    for (int kb = 0; kb < 256; kb += 64) {
        // convert + write staged tiles
#pragma unroll
        for (int it = 0; it < 2; ++it) {
            short8 hi, lo;
#pragma unroll
            for (int k = 0; k < 4; ++k) {
                float f0 = leakyf(av0[it][k] * rdv[it]);
                float f1 = leakyf(av1[it][k] * rdv[it]);
                short h0 = f2b(f0); hi[k] = h0; lo[k] = f2b(f0 - b2f(h0));
                short h1 = f2b(f1); hi[4 + k] = h1; lo[4 + k] = f2b(f1 - b2f(h1));
            }
            *reinterpret_cast<short8*>(&Ash[rS[it]][cS[it]]) = hi;
            *reinterpret_cast<short8*>(&Asl[rS[it]][cS[it]]) = lo;
            *reinterpret_cast<short8*>(&Bsh[rS[it]][cS[it]]) = bvh[it];
            *reinterpret_cast<short8*>(&Bsl[rS[it]][cS[it]]) = bvl[it];
        }
        __syncthreads();
        // prefetch next step
        const bool pf = (kb < 192);
        f32x4 an0[2], an1[2];
        short8 bnh[2], bnl[2];
        if (pf) {
#pragma unroll
            for (int it = 0; it < 2; ++it) {
                const float* ap = C1 + (j0 + rS[it]) * 288 + kb + 64 + cS[it];
                an0[it] = *reinterpret_cast<const f32x4*>(ap);
                an1[it] = *reinterpret_cast<const f32x4*>(ap + 4);
                bnh[it] = *reinterpret_cast<const short8*>(w2Th + (d0 + rS[it]) * 256 + kb + 64 + cS[it]);
                bnl[it] = *reinterpret_cast<const short8*>(w2Tl + (d0 + rS[it]) * 256 + kb + 64 + cS[it]);
            }
        }
#pragma unroll
        for (int ks = 0; ks < 2; ++ks) {
            short8 ah[2], al[2], bh[2], bl[2];
#pragma unroll
            for (int i = 0; i < 2; ++i) {
                ah[i] = *reinterpret_cast<const short8*>(&Ash[wm * 32 + i * 16 + l15][ks * 32 + quad * 8]);
                al[i] = *reinterpret_cast<const short8*>(&Asl[wm * 32 + i * 16 + l15][ks * 32 + quad * 8]);
            }
#pragma unroll
            for (int j = 0; j < 2; ++j) {
                bh[j] = *reinterpret_cast<const short8*>(&Bsh[wn * 32 + j * 16 + l15][ks * 32 + quad * 8]);
                bl[j] = *reinterpret_cast<const short8*>(&Bsl[wn * 32 + j * 16 + l15][ks * 32 + quad * 8]);
            }
#pragma unroll
            for (int i = 0; i < 2; ++i)
#pragma unroll
                for (int j = 0; j < 2; ++j) {
                    acc[i][j] = __builtin_amdgcn_mfma_f32_16x16x32_bf16(ah[i], bh[j], acc[i][j], 0, 0, 0);
                    acc[i][j] = __builtin_amdgcn_mfma_f32_16x16x32_bf16(ah[i], bl[j], acc[i][j], 0, 0, 0);
                    acc[i][j] = __builtin_amdgcn_mfma_f32_16x16x32_bf16(al[i], bh[j], acc[i][j], 0, 0, 0);
                }
        }
        __syncthreads();
        if (pf) {
#pragma unroll
            for (int it = 0; it < 2; ++it) {
                av0[it] = an0[it]; av1[it] = an1[it];
                bvh[it] = bnh[it]; bvl[it] = bnl[it];
            }
        }
    }
#pragma unroll
    for (int i = 0; i < 2; ++i)
#pragma unroll
        for (int j = 0; j < 2; ++j)
#pragma unroll
            for (int r = 0; r < 4; ++r)
                Gs[wm * 32 + i * 16 + quad * 4 + r][wn * 32 + j * 16 + l15] = acc[i][j][r];
    __syncthreads();
    {
        const int jl = t >> 2, q = t & 3;
        float cp = 0.f;
#pragma unroll
        for (int i = 0; i < 16; ++i) {
            const int d = q * 16 + i;
            cp += leakyf(Gs[jl][d]) * a21[d0 + d];
        }
        cp += __shfl_xor(cp, 1); cp += __shfl_xor(cp, 2);
        if (q == 0) atomicAdd(&cat[j0 + jl], cp);
    }
    {
        const int dl = t >> 2, q = t & 3;
        short8 pk0, pk1;
#pragma unroll
        for (int i = 0; i < 8; ++i) pk0[i] = f2b(Gs[q * 16 + i][dl]);
#pragma unroll
        for (int i = 0; i < 8; ++i) pk1[i] = f2b(Gs[q * 16 + 8 + i][dl]);
        short* gp = GT + (d0 + dl) * 4096 + j0 + q * 16;
        *reinterpret_cast<short8*>(gp) = pk0;
        *reinterpret_cast<short8*>(gp + 8) = pk1;
    }
}

// ---------------------------------------------------------------- FUSED edge weights + final GEMM, j-split (z=2)
// BM=64, BN=256, BK=64, Ktile=2048 (z=2), 512 threads, grid (256,2) = 512 blocks.
__global__ __launch_bounds__(512, 4) void fused_out_split(
        const unsigned int* __restrict__ Hbits, const float* __restrict__ cat,
        const float* __restrict__ dn, const short* __restrict__ GT,
        float* __restrict__ outP, float* __restrict__ rsP) {
    __shared__ short As[64][72];    // 9.2 KB
    __shared__ short Bs[256][72];   // 36.9 KB
    __shared__ float rsS[64][8];
    const int t = threadIdx.x;
    const int wid = t >> 6, lane = t & 63;
    const int wm = wid >> 2, wn = wid & 3;    // 2 m-groups x 4 n-groups
    const int quad = lane >> 4, l15 = lane & 15;
    const long m0 = (long)blockIdx.x * 64;
    const int z = blockIdx.y;
    const int kbase = z * 2048;
    const int r = t & 63, c8 = t >> 6;        // B-value role: row r, 8-col chunk c8
    const float drow = dn[m0 + r];
    const int bo = (c8 & 3) * 8;

    f32x4 acc[2][4];
#pragma unroll
    for (int i = 0; i < 2; ++i)
#pragma unroll
        for (int j = 0; j < 4; ++j)
#pragma unroll
            for (int x = 0; x < 4; ++x) acc[i][j][x] = 0.f;
    float racc = 0.f;

    short8 gv[4];   // staged GT tile regs
    short8 pkc;     // staged edge-weight bf16 octet
    // prologue: load + compute step 0
    {
        const int kb = kbase;
#pragma unroll
        for (int it = 0; it < 4; ++it) {
            const int cid = t + it * 512;
            const int row = cid >> 3, cc = (cid & 7) * 8;
            gv[it] = *reinterpret_cast<const short8*>(GT + row * 4096 + kb + cc);
        }
        const unsigned int w = Hbits[(m0 + r) * 128 + (kb >> 5) + (c8 >> 2)];
        const f32x4 cv0 = *reinterpret_cast<const f32x4*>(cat + kb + c8 * 8);
        const f32x4 cv1 = *reinterpret_cast<const f32x4*>(cat + kb + c8 * 8 + 4);
#pragma unroll
        for (int k = 0; k < 8; ++k) {
            const float cvk = (k < 4) ? cv0[k & 3] : cv1[k & 3];
            const float s = ((w >> (bo + k)) & 1u) ? satexpf(cvk + drow) : 0.f;
            const short sb = f2b(s);
            pkc[k] = sb;
            racc += b2f(sb);
        }
    }

    for (int kk = 0; kk < 2048; kk += 64) {
        const int kb = kbase + kk;
        // write staged tile for this step
#pragma unroll
        for (int it = 0; it < 4; ++it) {
            const int cid = t + it * 512;
            const int row = cid >> 3, cc = (cid & 7) * 8;
            *reinterpret_cast<short8*>(&Bs[row][cc]) = gv[it];
        }
        *reinterpret_cast<short8*>(&As[r][c8 * 8]) = pkc;
        __syncthreads();

        // prefetch step k+1 (loads fly under the MFMA cluster)
        const bool pf = (kk < 1984);
        unsigned int hw = 0u;
        f32x4 cn0{}, cn1{};
        if (pf) {
            const int kn = kb + 64;
#pragma unroll
            for (int it = 0; it < 4; ++it) {
                const int cid = t + it * 512;
                const int row = cid >> 3, cc = (cid & 7) * 8;
                gv[it] = *reinterpret_cast<const short8*>(GT + row * 4096 + kn + cc);
            }
            hw = Hbits[(m0 + r) * 128 + (kn >> 5) + (c8 >> 2)];
            cn0 = *reinterpret_cast<const f32x4*>(cat + kn + c8 * 8);
            cn1 = *reinterpret_cast<const f32x4*>(cat + kn + c8 * 8 + 4);
        }

#pragma unroll
        for (int ks = 0; ks < 2; ++ks) {
            short8 af[2], bf[4];
#pragma unroll
            for (int i = 0; i < 2; ++i)
                af[i] = *reinterpret_cast<const short8*>(
                        &As[wm * 32 + i * 16 + l15][ks * 32 + quad * 8]);
#pragma unroll
            for (int j = 0; j < 4; ++j)
                bf[j] = *reinterpret_cast<const short8*>(
                        &Bs[wn * 64 + j * 16 + l15][ks * 32 + quad * 8]);
#pragma unroll
            for (int i = 0; i < 2; ++i)
#pragma unroll
                for (int j = 0; j < 4; ++j)
                    acc[i][j] = __builtin_amdgcn_mfma_f32_16x16x32_bf16(
                            af[i], bf[j], acc[i][j], 0, 0, 0);
        }

        // compute next step's edge weights (load results have had MFMA time to land)
        if (pf) {
#pragma unroll
            for (int k = 0; k < 8; ++k) {
                const float cvk = (k < 4) ? cn0[k & 3] : cn1[k & 3];
                const float s = ((hw >> (bo + k)) & 1u) ? satexpf(cvk + drow) : 0.f;
                const short sb = f2b(s);
                pkc[k] = sb;
                racc += b2f(sb);
            }
        }
        __syncthreads();
    }
    rsS[r][c8] = racc;
    __syncthreads();
    if (t < 64) {
        float s = 0.f;
#pragma unroll
        for (int i = 0; i < 8; ++i) s += rsS[t][i];
        rsP[z * 16384 + m0 + t] = s;
    }
    float* op = outP + (long)z * (16384L * 256);
#pragma unroll
    for (int i = 0; i < 2; ++i) {
#pragma unroll
        for (int j = 0; j < 4; ++j) {
            const long gcol = wn * 64 + j * 16 + l15;
#pragma unroll
            for (int x = 0; x < 4; ++x) {
                const long grow = m0 + wm * 32 + i * 16 + quad * 4 + x;
                op[grow * 256 + gcol] = acc[i][j][x];
            }
        }
    }
}

// ---------------------------------------------------------------- combine: out = leaky(sum_z outP / sum_z rsP)  (z=2)
__global__ __launch_bounds__(256) void combine_out(
        const float* __restrict__ outP, const float* __restrict__ rsP,
        float* __restrict__ out) {
    const long i = ((long)blockIdx.x * 256 + threadIdx.x) * 4;  // grid 4096
    const long n = i >> 8;
    f32x4 s = *reinterpret_cast<const f32x4*>(outP + i);
    {
        f32x4 v = *reinterpret_cast<const f32x4*>(outP + (16384L * 256) + i);
#pragma unroll
        for (int k = 0; k < 4; ++k) s[k] += v[k];
    }
    const float rinv = fastrcp(rsP[n] + rsP[16384 + n]);
    f32x4 o;
#pragma unroll
    for (int k = 0; k < 4; ++k) o[k] = leakyf(s[k] * rinv);
    *reinterpret_cast<f32x4*>(out + i) = o;
}

// ---------------------------------------------------------------- launch
extern "C" void kernel_launch(void* const* d_in, const int* in_sizes, int n_in,
                              void* d_out, int out_size, void* d_ws, size_t ws_size,
                              hipStream_t stream) {
    const float* x   = (const float*)d_in[0];
    const float* H   = (const float*)d_in[1];
    const float* w1  = (const float*)d_in[2];
    const float* w2  = (const float*)d_in[3];
    const float* a1  = (const float*)d_in[4];
    const float* a21 = (const float*)d_in[5];
    const float* a22 = (const float*)d_in[6];
    float* out = (float*)d_out;
    char* ws = (char*)d_ws;

    // region0: xw1 fp32 (16.8MB) then C1p fp32 [8][4096][288] (37.75MB) -- sequential reuse
    float* xw1   = (float*)(ws + 0);
    float* C1p   = (float*)(ws + 0);
    char*  yQ    = (char*)(ws + 67108864);                // [576,16384] i8 (9.44MB)
    float* dn    = (float*)(ws + 76546048);               // [16384]
    float* g     = (float*)(ws + 76611584);               // [16384]
    unsigned int* ddmax = (unsigned int*)(ws + 76677120); // [288]
    short* w1Th  = (short*)(ws + 76681216);
    short* w1Tl  = (short*)(ws + 76812288);
    short* w2Th  = (short*)(ws + 76943360);
    short* w2Tl  = (short*)(ws + 77074432);
    float* C1    = (float*)(ws + 77205504);               // [4096,288]
    short* GT    = (short*)(ws + 81924096);               // [256,4096] bf16
    float* cat   = (float*)(ws + 84021248);               // [4096]
    unsigned int* Hbits  = (unsigned int*)(ws + 84037632);// [16384,128] (8MB)
    unsigned int* HbitsT = (unsigned int*)(ws + 92426240);// [4096,512]  (8MB)
    float* outP  = (float*)(ws + 134217728);              // [2][16384,256] (33.6MB)
    float* rsP   = (float*)(ws + 201326592);              // [2][16384]

    transpose_split2<<<dim3(4, 4, 2), 256, 0, stream>>>(
            w1, w1Th, w1Tl, w2, w2Th, w2Tl);
    transposeH_pack<<<dim3(256, 64), 256, 0, stream>>>(H, Hbits, HbitsT, ddmax, cat);

    gemm_xw1<<<dim3(128, 4), 256, 0, stream>>>(x, w1Th, w1Tl, xw1);
    node_stats1<<<dim3(256), 256, 0, stream>>>(xw1, a1, a22, g, dn, ddmax);
    quantize_y<<<dim3(256), 256, 0, stream>>>(xw1, g, ddmax, yQ);

    gemm_c1_bits<<<dim3(16, 6, 8), 256, 0, stream>>>(HbitsT, yQ, C1p);
    reduce_C1<<<dim3(4608), 256, 0, stream>>>(C1p, ddmax, C1);

    gemm_G<<<dim3(64, 4), 256, 0, stream>>>(C1, w2Th, w2Tl, a21, GT, cat);

    fused_out_split<<<dim3(256, 2), 512, 0, stream>>>(Hbits, cat, dn, GT, outP, rsP);
    combine_out<<<dim3(4096), 256, 0, stream>>>(outP, rsP, out);
}

// Round 17
// 587.584 us; speedup vs baseline: 1.0194x; 1.0066x over previous
//
#include <hip/hip_runtime.h>

// HyperGAT layer, N=16384, E=4096, D=256 on gfx950.
//   xw1 = x@w1 (split-bf16 MFMA, ~fp32 accurate)
//   g_n = satexp(leaky(xw1)@a1), d_n = leaky(xw1)@a22
//   y = g*xw1 quantized to i16 (per-dd global scale), split qh/ql i8 planes
//   C1 = H^T @ [qh|ql]  (i8 MFMA; A-fragments expanded from bit-pack IN REGISTERS)
//   f2 = leaky(C1/den);  G = f2@w2 (split);  c_j = leaky(G)@a21
//   out = leaky((B@G)/rowsum), B[n,j] = Hbit*satexp(c_j+d_n) on the fly,
//   j-split + combine epilogue.
// R3: T14 async-STAGE in gemm_c1_bits + fused_out_split (610.6 -> 598.9 us).
// R8: z=1 fused REGRESSED (625.5): 1 block/CU (8 waves) exposed barrier drains.
// R9: revert + T14 on gemm_xw1/gemm_G: 598.3 us (T14 there = null; kept).
// R11: fused z=4 -> z=2: 590.3 us (-8; 16 waves/CU keep overlap, outP halved).
// R12: atomic-C1 REGRESSED (599.0): C1p round-trip was L3-absorbed.
// R14/R16: revert verified (591.5/590.3). Lesson: L3-resident round-trips are
//   near-free; only HBM-visible traffic + launches count.
// R16: transpose_split2 FOLDED into transposeH_pack (blocks bx<4&&by<8 do the
//   weight transpose first, sequential LDS reuse) — one launch gap saved.

typedef __attribute__((ext_vector_type(8))) short short8;
typedef __attribute__((ext_vector_type(4))) short short4v;
typedef __attribute__((ext_vector_type(4))) float f32x4;
typedef __attribute__((ext_vector_type(4))) int int4v;
typedef __attribute__((ext_vector_type(4))) unsigned int uint4v;

__device__ __forceinline__ float leakyf(float v) { return v > 0.f ? v : 0.1f * v; }
__device__ __forceinline__ float fastrcp(float x) { return __builtin_amdgcn_rcpf(x); }

__device__ __forceinline__ float satexpf(float t) {
    float u = fminf(fmaxf(t * 0.25f, -30.f), 30.f);
    float p = __expf(u);
    float th = (p - 1.f) * fastrcp(p + 1.f);
    return __expf(8.f * th);
}

__device__ __forceinline__ short f2b(float v) {
    unsigned int x = __float_as_uint(v);
    x += 0x7fffu + ((x >> 16) & 1u);
    return (short)(x >> 16);
}
__device__ __forceinline__ float b2f(short s) {
    return __uint_as_float(((unsigned int)(unsigned short)s) << 16);
}
// 4 H-bits -> 4 i8 bytes (bit-deposit via magic multiply)
__device__ __forceinline__ unsigned int bits4_to_bytes(unsigned int s) {
    return ((s & 0xFu) * 0x00204081u) & 0x01010101u;
}

// ---------------------------------------------------------------- H -> Hbits + HbitsT; folds: ddmax/cat zero, w1/w2 transpose+split (R16)
__global__ __launch_bounds__(256) void transposeH_pack(
        const float* __restrict__ H, unsigned int* __restrict__ Hbits,
        unsigned int* __restrict__ HbitsT, unsigned int* __restrict__ ddmax,
        float* __restrict__ cat,
        const float* __restrict__ w1, short* __restrict__ w1Th, short* __restrict__ w1Tl,
        const float* __restrict__ w2, short* __restrict__ w2Th, short* __restrict__ w2Tl) {
    __shared__ float Ts[64][65];
    const int t = threadIdx.x;
    const long r0 = (long)blockIdx.x * 64;   // n
    const long c0 = (long)blockIdx.y * 64;   // j
    if (blockIdx.x == 0 && blockIdx.y == 0) {   // fold the two memsets
        if (t < 256) ddmax[t] = 0u;
        if (t < 32) ddmax[256 + t] = 0u;
#pragma unroll
        for (int i = 0; i < 16; ++i) cat[t * 16 + i] = 0.f;
    }
    // R16: folded weight transpose — 32 blocks, sequential LDS reuse.
    if (blockIdx.x < 4 && blockIdx.y < 8) {
        const int zz = blockIdx.y >> 2;
        const float* src = zz ? w2 : w1;
        short* dh = zz ? w2Th : w1Th;
        short* dl = zz ? w2Tl : w1Tl;
        const long sr0 = (long)blockIdx.x * 64;
        const long sc0 = (long)(blockIdx.y & 3) * 64;
        {
            const int row = t >> 2, cc = (t & 3) * 16;
            const float* p = src + (sr0 + row) * 256 + sc0 + cc;
#pragma unroll
            for (int i = 0; i < 4; ++i) {
                f32x4 v = *reinterpret_cast<const f32x4*>(p + i * 4);
#pragma unroll
                for (int k = 0; k < 4; ++k) Ts[row][cc + i * 4 + k] = v[k];
            }
        }
        __syncthreads();
        {
            const int cl = t >> 2, ch = (t & 3) * 16;
            short8 h0, h1, l0, l1;
#pragma unroll
            for (int i = 0; i < 8; ++i) {
                float v = Ts[ch + i][cl];
                short h = f2b(v);
                h0[i] = h; l0[i] = f2b(v - b2f(h));
            }
#pragma unroll
            for (int i = 0; i < 8; ++i) {
                float v = Ts[ch + 8 + i][cl];
                short h = f2b(v);
                h1[i] = h; l1[i] = f2b(v - b2f(h));
            }
            short* qh = dh + (sc0 + cl) * 256 + sr0 + ch;
            short* ql = dl + (sc0 + cl) * 256 + sr0 + ch;
            *reinterpret_cast<short8*>(qh) = h0;
            *reinterpret_cast<short8*>(qh + 8) = h1;
            *reinterpret_cast<short8*>(ql) = l0;
            *reinterpret_cast<short8*>(ql + 8) = l1;
        }
        __syncthreads();   // protect Ts reuse by the H part below
    }
    {
        const int row = t >> 2, cc = (t & 3) * 16;
        const float* p = H + (r0 + row) * 4096L + c0 + cc;
#pragma unroll
        for (int i = 0; i < 4; ++i) {
            f32x4 v = *reinterpret_cast<const f32x4*>(p + i * 4);
#pragma unroll
            for (int k = 0; k < 4; ++k) Ts[row][cc + i * 4 + k] = v[k];
        }
    }
    __syncthreads();
    if (t < 128) {           // Hbits: row n, bits over j
        const int nl = t >> 1, w = t & 1;
        unsigned int u = 0;
#pragma unroll
        for (int b = 0; b < 32; ++b)
            u |= (Ts[nl][w * 32 + b] != 0.f ? 1u : 0u) << b;
        Hbits[(r0 + nl) * 128 + (c0 >> 5) + w] = u;
    } else {                 // HbitsT: row j, bits over n
        const int t2 = t - 128;
        const int jl = t2 >> 1, w = t2 & 1;
        unsigned int u = 0;
#pragma unroll
        for (int b = 0; b < 32; ++b)
            u |= (Ts[w * 32 + b][jl] != 0.f ? 1u : 0u) << b;
        HbitsT[(c0 + jl) * 512 + (r0 >> 5) + w] = u;
    }
}

// ---------------------------------------------------------------- xw1 split GEMM (fp32-accurate)
// R9: T14 — A/B tiles for step k+1 loaded into regs under the MFMA cluster.
__global__ __launch_bounds__(256) void gemm_xw1(
        const float* __restrict__ A, const short* __restrict__ Bh,
        const short* __restrict__ Bl, float* __restrict__ C) {
    __shared__ short Ash[128][72];
    __shared__ short Asl[128][72];
    __shared__ short Bsh[64][72];
    __shared__ short Bsl[64][72];
    const int t = threadIdx.x;
    const int wid = t >> 6, lane = t & 63;
    const int wm = wid & 1, wn = wid >> 1;
    const int quad = lane >> 4, l15 = lane & 15;
    const long m0 = (long)blockIdx.x * 128;
    const long n0 = (long)blockIdx.y * 64;
    // fixed per-thread staging descriptors
    int rA[4], cA[4], rB[2], cB[2];
#pragma unroll
    for (int it = 0; it < 4; ++it) {
        const int cid = t + it * 256;
        rA[it] = cid >> 3; cA[it] = (cid & 7) * 8;
    }
#pragma unroll
    for (int it = 0; it < 2; ++it) {
        const int cid = t + it * 256;
        rB[it] = cid >> 3; cB[it] = (cid & 7) * 8;
    }
    f32x4 acc[4][2];
#pragma unroll
    for (int i = 0; i < 4; ++i)
#pragma unroll
        for (int j = 0; j < 2; ++j)
#pragma unroll
            for (int r = 0; r < 4; ++r) acc[i][j][r] = 0.f;

    // prologue: load kb=0 tiles into regs
    f32x4 av0[4], av1[4];
    short8 bvh[2], bvl[2];
#pragma unroll
    for (int it = 0; it < 4; ++it) {
        const float* ap = A + (m0 + rA[it]) * 256 + cA[it];
        av0[it] = *reinterpret_cast<const f32x4*>(ap);
        av1[it] = *reinterpret_cast<const f32x4*>(ap + 4);
    }
#pragma unroll
    for (int it = 0; it < 2; ++it) {
        bvh[it] = *reinterpret_cast<const short8*>(Bh + (n0 + rB[it]) * 256 + cB[it]);
        bvl[it] = *reinterpret_cast<const short8*>(Bl + (n0 + rB[it]) * 256 + cB[it]);
    }

    for (int kb = 0; kb < 256; kb += 64) {
        // convert + write staged tiles
#pragma unroll
        for (int it = 0; it < 4; ++it) {
            short8 hi, lo;
#pragma unroll
            for (int k = 0; k < 4; ++k) {
                short h0 = f2b(av0[it][k]); hi[k] = h0; lo[k] = f2b(av0[it][k] - b2f(h0));
                short h1 = f2b(av1[it][k]); hi[4 + k] = h1; lo[4 + k] = f2b(av1[it][k] - b2f(h1));
            }
            *reinterpret_cast<short8*>(&Ash[rA[it]][cA[it]]) = hi;
            *reinterpret_cast<short8*>(&Asl[rA[it]][cA[it]]) = lo;
        }
#pragma unroll
        for (int it = 0; it < 2; ++it) {
            *reinterpret_cast<short8*>(&Bsh[rB[it]][cB[it]]) = bvh[it];
            *reinterpret_cast<short8*>(&Bsl[rB[it]][cB[it]]) = bvl[it];
        }
        __syncthreads();
        // prefetch next step (flies under the MFMA cluster)
        const bool pf = (kb < 192);
        f32x4 an0[4], an1[4];
        short8 bnh[2], bnl[2];
        if (pf) {
#pragma unroll
            for (int it = 0; it < 4; ++it) {
                const float* ap = A + (m0 + rA[it]) * 256 + kb + 64 + cA[it];
                an0[it] = *reinterpret_cast<const f32x4*>(ap);
                an1[it] = *reinterpret_cast<const f32x4*>(ap + 4);
            }
#pragma unroll
            for (int it = 0; it < 2; ++it) {
                bnh[it] = *reinterpret_cast<const short8*>(Bh + (n0 + rB[it]) * 256 + kb + 64 + cB[it]);
                bnl[it] = *reinterpret_cast<const short8*>(Bl + (n0 + rB[it]) * 256 + kb + 64 + cB[it]);
            }
        }
#pragma unroll
        for (int ks = 0; ks < 2; ++ks) {
            short8 ah[4], al[4], bh[2], bl[2];
#pragma unroll
            for (int i = 0; i < 4; ++i) {
                ah[i] = *reinterpret_cast<const short8*>(&Ash[wm * 64 + i * 16 + l15][ks * 32 + quad * 8]);
                al[i] = *reinterpret_cast<const short8*>(&Asl[wm * 64 + i * 16 + l15][ks * 32 + quad * 8]);
            }
#pragma unroll
            for (int j = 0; j < 2; ++j) {
                bh[j] = *reinterpret_cast<const short8*>(&Bsh[wn * 32 + j * 16 + l15][ks * 32 + quad * 8]);
                bl[j] = *reinterpret_cast<const short8*>(&Bsl[wn * 32 + j * 16 + l15][ks * 32 + quad * 8]);
            }
#pragma unroll
            for (int i = 0; i < 4; ++i)
#pragma unroll
                for (int j = 0; j < 2; ++j) {
                    acc[i][j] = __builtin_amdgcn_mfma_f32_16x16x32_bf16(ah[i], bh[j], acc[i][j], 0, 0, 0);
                    acc[i][j] = __builtin_amdgcn_mfma_f32_16x16x32_bf16(ah[i], bl[j], acc[i][j], 0, 0, 0);
                    acc[i][j] = __builtin_amdgcn_mfma_f32_16x16x32_bf16(al[i], bh[j], acc[i][j], 0, 0, 0);
                }
        }
        __syncthreads();
        if (pf) {
#pragma unroll
            for (int it = 0; it < 4; ++it) { av0[it] = an0[it]; av1[it] = an1[it]; }
#pragma unroll
            for (int it = 0; it < 2; ++it) { bvh[it] = bnh[it]; bvl[it] = bnl[it]; }
        }
    }
#pragma unroll
    for (int i = 0; i < 4; ++i) {
        const long grow = m0 + wm * 64 + i * 16 + quad * 4;
#pragma unroll
        for (int j = 0; j < 2; ++j) {
            const long gcol = n0 + wn * 32 + j * 16 + l15;
#pragma unroll
            for (int r = 0; r < 4; ++r)
                C[(grow + r) * 256 + gcol] = acc[i][j][r];
        }
    }
}

// ---------------------------------------------------------------- node stats: g, dn, per-dd |y| max
__global__ __launch_bounds__(256) void node_stats1(
        const float* __restrict__ xw1, const float* __restrict__ a1,
        const float* __restrict__ a22, float* __restrict__ g_out,
        float* __restrict__ dn, unsigned int* __restrict__ ddmax) {
    __shared__ float Mx[4][260];
    const int t = threadIdx.x;
    const int n0 = blockIdx.x * 64;
    const int r = t >> 2, q = t & 3;
    const long n = n0 + r;
    const float* xp = xw1 + n * 256 + q * 64;
    float vals[64];
    float facc = 0.f, dacc = 0.f;
#pragma unroll
    for (int i = 0; i < 16; ++i) {
        f32x4 v  = *reinterpret_cast<const f32x4*>(xp + i * 4);
        f32x4 b1 = *reinterpret_cast<const f32x4*>(a1 + q * 64 + i * 4);
        f32x4 b2 = *reinterpret_cast<const f32x4*>(a22 + q * 64 + i * 4);
#pragma unroll
        for (int k = 0; k < 4; ++k) {
            float lv = leakyf(v[k]);
            facc += lv * b1[k];
            dacc += lv * b2[k];
            vals[i * 4 + k] = v[k];
        }
    }
    facc += __shfl_xor(facc, 1); facc += __shfl_xor(facc, 2);
    dacc += __shfl_xor(dacc, 1); dacc += __shfl_xor(dacc, 2);
    const float g = satexpf(facc);
    if (q == 0) { dn[n] = dacc; g_out[n] = g; }
    float lm[64];
#pragma unroll
    for (int i = 0; i < 64; ++i) lm[i] = fabsf(vals[i] * g);
#pragma unroll
    for (int m = 4; m < 64; m <<= 1)
#pragma unroll
        for (int i = 0; i < 64; ++i) lm[i] = fmaxf(lm[i], __shfl_xor(lm[i], m));
    float gm = g;
#pragma unroll
    for (int m = 1; m < 64; m <<= 1) gm = fmaxf(gm, __shfl_xor(gm, m));
    const int wv = t >> 6, lane = t & 63;
    if (lane < 4) {
#pragma unroll
        for (int i = 0; i < 64; ++i) Mx[wv][lane * 64 + i] = lm[i];
    }
    if (lane == 0) Mx[wv][256] = gm;
    __syncthreads();
    if (t < 256) {
        float m = fmaxf(fmaxf(Mx[0][t], Mx[1][t]), fmaxf(Mx[2][t], Mx[3][t]));
        atomicMax(&ddmax[t], __float_as_uint(m));
    }
    if (t == 0) {  // index 256 (g); block has only 256 threads
        float m = fmaxf(fmaxf(Mx[0][256], Mx[1][256]), fmaxf(Mx[2][256], Mx[3][256]));
        atomicMax(&ddmax[256], __float_as_uint(m));
    }
}

// ---------------------------------------------------------------- quantize y -> yQ i8 [576,16384]
__global__ __launch_bounds__(256) void quantize_y(
        const float* __restrict__ xw1, const float* __restrict__ g_in,
        const unsigned int* __restrict__ ddmax, char* __restrict__ yQ) {
    __shared__ unsigned int Qh[257][16];
    __shared__ unsigned int Ql[257][16];
    const int t = threadIdx.x;
    const int n0 = blockIdx.x * 64;
    const int dd0 = (t >> 4) * 16;
    const int w = t & 15;
    const int r4 = w * 4;
    float s[16];
#pragma unroll
    for (int i = 0; i < 16; ++i)
        s[i] = 32512.f / __uint_as_float(ddmax[dd0 + i]);
    const float sg = 32512.f / __uint_as_float(ddmax[256]);
    unsigned int bh[16], bl[16];
#pragma unroll
    for (int i = 0; i < 16; ++i) { bh[i] = 0u; bl[i] = 0u; }
    unsigned int gh = 0u, gl = 0u;
#pragma unroll
    for (int rr = 0; rr < 4; ++rr) {
        const long n = n0 + r4 + rr;
        const float gg = g_in[n];
        const float* xp = xw1 + n * 256 + dd0;
#pragma unroll
        for (int c = 0; c < 4; ++c) {
            f32x4 v = *reinterpret_cast<const f32x4*>(xp + c * 4);
#pragma unroll
            for (int k = 0; k < 4; ++k) {
                const int i = c * 4 + k;
                int qv = __float2int_rn(v[k] * gg * s[i]);
                qv = max(-32639, min(32639, qv));
                const int qh = (qv + 128) >> 8;
                const int ql = qv - (qh << 8);
                bh[i] |= ((unsigned int)(qh & 255)) << (8 * rr);
                bl[i] |= ((unsigned int)(ql & 255)) << (8 * rr);
            }
        }
        if (t < 16) {
            int qv = __float2int_rn(gg * sg);
            qv = max(-32639, min(32639, qv));
            const int qh = (qv + 128) >> 8;
            const int ql = qv - (qh << 8);
            gh |= ((unsigned int)(qh & 255)) << (8 * rr);
            gl |= ((unsigned int)(ql & 255)) << (8 * rr);
        }
    }
#pragma unroll
    for (int i = 0; i < 16; ++i) { Qh[dd0 + i][w] = bh[i]; Ql[dd0 + i][w] = bl[i]; }
    if (t < 16) { Qh[256][t] = gh; Ql[256][t] = gl; }
    __syncthreads();
#pragma unroll
    for (int it = 0; it < 2; ++it) {
        const int dd = it * 256 + t;
        if (dd < 288) {
#pragma unroll
            for (int s2 = 0; s2 < 4; ++s2) {
                uint4v vh, vl;
                if (dd < 257) {
                    vh = *reinterpret_cast<const uint4v*>(&Qh[dd][s2 * 4]);
                    vl = *reinterpret_cast<const uint4v*>(&Ql[dd][s2 * 4]);
                } else {
#pragma unroll
                    for (int k = 0; k < 4; ++k) { vh[k] = 0u; vl[k] = 0u; }
                }
                *reinterpret_cast<uint4v*>(yQ + (long)dd * 16384 + n0 + s2 * 16) = vh;
                *reinterpret_cast<uint4v*>(yQ + (long)(288 + dd) * 16384 + n0 + s2 * 16) = vl;
            }
        }
    }
}

// ---------------------------------------------------------------- C1 GEMM, i8 MFMA, A-fragments expanded IN REGISTERS
// BM=256 (j), BN=48 (dd), BK=128, z=8 (Ktile 2048), grid (16, 6, 8) = 768 blocks.
// R3: B-staging + bit-loads for step k+1 prefetched into regs during MFMA of k.
__global__ __launch_bounds__(256) void gemm_c1_bits(
        const unsigned int* __restrict__ HbitsT, const char* __restrict__ Bb,
        float* __restrict__ Cp) {
    __shared__ char Bsh[48][144];   // 6.9 KB
    __shared__ char Bsl[48][144];   // 6.9 KB
    const int t = threadIdx.x;
    const int wid = t >> 6, lane = t & 63;
    const int quad = lane >> 4, l15 = lane & 15;
    const long m0 = (long)blockIdx.x * 256;
    const long n0 = (long)blockIdx.y * 48;
    const long k0 = (long)blockIdx.z * 2048;
    float* Cz = Cp + (long)blockIdx.z * (4096L * 288);
    // this lane's 4 A-rows (j indices): m0 + wid*64 + i*16 + l15
    const unsigned int* bp[4];
#pragma unroll
    for (int i = 0; i < 4; ++i)
        bp[i] = HbitsT + (m0 + wid * 64 + i * 16 + l15) * 512 + (k0 >> 5);
    // staging descriptors (fixed per thread; round-6 bugfix kept: explicit compare)
    char* dstp[3];
    long sbase[3];
#pragma unroll
    for (int it = 0; it < 3; ++it) {
        const int cid = t + it * 256;
        const int idx = (cid < 384) ? cid : cid - 384;
        const int row = idx >> 3, seg = (idx & 7) * 16;
        dstp[it] = (cid >= 384) ? &Bsl[row][seg] : &Bsh[row][seg];
        const long srow = (cid >= 384) ? (288 + n0 + row) : (n0 + row);
        sbase[it] = srow * 16384 + k0 + seg;
    }
    int4v acch[4][3], accl[4][3];
#pragma unroll
    for (int i = 0; i < 4; ++i)
#pragma unroll
        for (int j = 0; j < 3; ++j)
#pragma unroll
            for (int r = 0; r < 4; ++r) { acch[i][j][r] = 0; accl[i][j][r] = 0; }

    // prologue: load bit-words + staged B regs for kb=0
    uint4v bv[4], sv[3];
#pragma unroll
    for (int i = 0; i < 4; ++i)
        bv[i] = *reinterpret_cast<const uint4v*>(bp[i]);
#pragma unroll
    for (int it = 0; it < 3; ++it)
        sv[it] = *reinterpret_cast<const uint4v*>(Bb + sbase[it]);

    for (int kb = 0; kb < 2048; kb += 128) {
        // write current staged tile to LDS
#pragma unroll
        for (int it = 0; it < 3; ++it)
            *reinterpret_cast<uint4v*>(dstp[it]) = sv[it];
        __syncthreads();
        // prefetch next step (overlaps the MFMA cluster below)
        const bool pf = (kb < 1920);
        uint4v bvn[4], svn[3];
        if (pf) {
#pragma unroll
            for (int i = 0; i < 4; ++i)
                bvn[i] = *reinterpret_cast<const uint4v*>(bp[i] + ((kb + 128) >> 5));
#pragma unroll
            for (int it = 0; it < 3; ++it)
                svn[it] = *reinterpret_cast<const uint4v*>(Bb + sbase[it] + kb + 128);
        }
#pragma unroll
        for (int ks = 0; ks < 2; ++ks) {
            int4v af[4], bh[3], bl[3];
#pragma unroll
            for (int i = 0; i < 4; ++i) {
                const unsigned int u =
                    bv[i][ks * 2 + (quad >> 1)] >> ((quad & 1) * 16);
                uint4v e;
#pragma unroll
                for (int k = 0; k < 4; ++k) e[k] = bits4_to_bytes(u >> (4 * k));
                af[i] = __builtin_bit_cast(int4v, e);
            }
#pragma unroll
            for (int j = 0; j < 3; ++j) {
                bh[j] = *reinterpret_cast<const int4v*>(&Bsh[j * 16 + l15][ks * 64 + quad * 16]);
                bl[j] = *reinterpret_cast<const int4v*>(&Bsl[j * 16 + l15][ks * 64 + quad * 16]);
            }
#pragma unroll
            for (int i = 0; i < 4; ++i)
#pragma unroll
                for (int j = 0; j < 3; ++j) {
                    acch[i][j] = __builtin_amdgcn_mfma_i32_16x16x64_i8(af[i], bh[j], acch[i][j], 0, 0, 0);
                    accl[i][j] = __builtin_amdgcn_mfma_i32_16x16x64_i8(af[i], bl[j], accl[i][j], 0, 0, 0);
                }
        }
        __syncthreads();
        if (pf) {
#pragma unroll
            for (int i = 0; i < 4; ++i) bv[i] = bvn[i];
#pragma unroll
            for (int it = 0; it < 3; ++it) sv[it] = svn[it];
        }
    }
#pragma unroll
    for (int i = 0; i < 4; ++i) {
        const long grow = m0 + wid * 64 + i * 16 + quad * 4;
#pragma unroll
        for (int j = 0; j < 3; ++j) {
            const long gcol = n0 + j * 16 + l15;
#pragma unroll
            for (int r = 0; r < 4; ++r)
                Cz[(grow + r) * 288 + gcol] =
                    256.f * (float)acch[i][j][r] + (float)accl[i][j][r];
        }
    }
}

// ---------------------------------------------------------------- reduce split-K partials + reconstruct scale
__global__ __launch_bounds__(256) void reduce_C1(
        const float* __restrict__ C1p, const unsigned int* __restrict__ ddmax,
        float* __restrict__ C1) {
    const int i = blockIdx.x * 256 + threadIdx.x;   // < 4096*288
    const int dd = i % 288;
    float s = 0.f;
#pragma unroll
    for (int z = 0; z < 8; ++z) s += C1p[(long)z * 4096 * 288 + i];
    C1[i] = s * (__uint_as_float(ddmax[dd]) * (1.f / 32512.f));
}

// ---------------------------------------------------------------- G = f2@w2 split (+ GT bf16, c_j)
// R9: T14 — A/B tiles for step k+1 loaded into regs under the MFMA cluster;
// per-row rcp(den) hoisted out of the K-loop (kb-invariant).
__global__ __launch_bounds__(256) void gemm_G(
        const float* __restrict__ C1, const short* __restrict__ w2Th,
        const short* __restrict__ w2Tl, const float* __restrict__ a21,
        short* __restrict__ GT, float* __restrict__ cat) {
    __shared__ short Ash[64][72];
    __shared__ short Asl[64][72];
    __shared__ short Bsh[64][72];
    __shared__ short Bsl[64][72];
    __shared__ float Gs[64][65];
    const int t = threadIdx.x;
    const int wid = t >> 6, lane = t & 63;
    const int wm = wid & 1, wn = wid >> 1;
    const int quad = lane >> 4, l15 = lane & 15;
    const long j0 = (long)blockIdx.x * 64;
    const long d0 = (long)blockIdx.y * 64;
    // fixed per-thread staging descriptors
    int rS[2], cS[2];
#pragma unroll
    for (int it = 0; it < 2; ++it) {
        const int cid = t + it * 256;
        rS[it] = cid >> 3; cS[it] = (cid & 7) * 8;
    }
    f32x4 acc[2][2];
#pragma unroll
    for (int i = 0; i < 2; ++i)
#pragma unroll
        for (int j = 0; j < 2; ++j)
#pragma unroll
            for (int r = 0; r < 4; ++r) acc[i][j][r] = 0.f;

    // prologue: rd (kb-invariant) + kb=0 tiles into regs
    float rdv[2];
    f32x4 av0[2], av1[2];
    short8 bvh[2], bvl[2];
#pragma unroll
    for (int it = 0; it < 2; ++it) {
        rdv[it] = fastrcp(C1[(j0 + rS[it]) * 288 + 256]);
        const float* ap = C1 + (j0 + rS[it]) * 288 + cS[it];
        av0[it] = *reinterpret_cast<const f32x4*>(ap);
        av1[it] = *reinterpret_cast<const f32x4*>(ap + 4);
        bvh[it] = *reinterpret_cast<const short8*>(w2Th + (d0 + rS[it]) * 256 + cS[it]);
        bvl[it] = *reinterpret_cast<const short8*>(w2Tl + (d0 + rS[it]) * 256 + cS[it]);
    }

    for (int kb = 0; kb < 256; kb += 64) {
        // convert + write staged tiles
#pragma unroll
        for (int it = 0; it < 2; ++it) {
            short8 hi, lo;
#pragma unroll
            for (int k = 0; k < 4; ++k) {
                float f0 = leakyf(av0[it][k] * rdv[it]);
                float f1 = leakyf(av1[it][k] * rdv[it]);
                short h0 = f2b(f0); hi[k] = h0; lo[k] = f2b(f0 - b2f(h0));
                short h1 = f2b(f1); hi[4 + k] = h1; lo[4 + k] = f2b(f1 - b2f(h1));
            }
            *reinterpret_cast<short8*>(&Ash[rS[it]][cS[it]]) = hi;
            *reinterpret_cast<short8*>(&Asl[rS[it]][cS[it]]) = lo;
            *reinterpret_cast<short8*>(&Bsh[rS[it]][cS[it]]) = bvh[it];
            *reinterpret_cast<short8*>(&Bsl[rS[it]][cS[it]]) = bvl[it];
        }
        __syncthreads();
        // prefetch next step
        const bool pf = (kb < 192);
        f32x4 an0[2], an1[2];
        short8 bnh[2], bnl[2];
        if (pf) {
#pragma unroll
            for (int it = 0; it < 2; ++it) {
                const float* ap = C1 + (j0 + rS[it]) * 288 + kb + 64 + cS[it];
                an0[it] = *reinterpret_cast<const f32x4*>(ap);
                an1[it] = *reinterpret_cast<const f32x4*>(ap + 4);
                bnh[it] = *reinterpret_cast<const short8*>(w2Th + (d0 + rS[it]) * 256 + kb + 64 + cS[it]);
                bnl[it] = *reinterpret_cast<const short8*>(w2Tl + (d0 + rS[it]) * 256 + kb + 64 + cS[it]);
            }
        }
#pragma unroll
        for (int ks = 0; ks < 2; ++ks) {
            short8 ah[2], al[2], bh[2], bl[2];
#pragma unroll
            for (int i = 0; i < 2; ++i) {
                ah[i] = *reinterpret_cast<const short8*>(&Ash[wm * 32 + i * 16 + l15][ks * 32 + quad * 8]);
                al[i] = *reinterpret_cast<const short8*>(&Asl[wm * 32 + i * 16 + l15][ks * 32 + quad * 8]);
            }
#pragma unroll
            for (int j = 0; j < 2; ++j) {
                bh[j] = *reinterpret_cast<const short8*>(&Bsh[wn * 32 + j * 16 + l15][ks * 32 + quad * 8]);
                bl[j] = *reinterpret_cast<const short8*>(&Bsl[wn * 32 + j * 16 + l15][ks * 32 + quad * 8]);
            }
#pragma unroll
            for (int i = 0; i < 2; ++i)
#pragma unroll
                for (int j = 0; j < 2; ++j) {
                    acc[i][j] = __builtin_amdgcn_mfma_f32_16x16x32_bf16(ah[i], bh[j], acc[i][j], 0, 0, 0);
                    acc[i][j] = __builtin_amdgcn_mfma_f32_16x16x32_bf16(ah[i], bl[j], acc[i][j], 0, 0, 0);
                    acc[i][j] = __builtin_amdgcn_mfma_f32_16x16x32_bf16(al[i], bh[j], acc[i][j], 0, 0, 0);
                }
        }
        __syncthreads();
        if (pf) {
#pragma unroll
            for (int it = 0; it < 2; ++it) {
                av0[it] = an0[it]; av1[it] = an1[it];
                bvh[it] = bnh[it]; bvl[it] = bnl[it];
            }
        }
    }
#pragma unroll
    for (int i = 0; i < 2; ++i)
#pragma unroll
        for (int j = 0; j < 2; ++j)
#pragma unroll
            for (int r = 0; r < 4; ++r)
                Gs[wm * 32 + i * 16 + quad * 4 + r][wn * 32 + j * 16 + l15] = acc[i][j][r];
    __syncthreads();
    {
        const int jl = t >> 2, q = t & 3;
        float cp = 0.f;
#pragma unroll
        for (int i = 0; i < 16; ++i) {
            const int d = q * 16 + i;
            cp += leakyf(Gs[jl][d]) * a21[d0 + d];
        }
        cp += __shfl_xor(cp, 1); cp += __shfl_xor(cp, 2);
        if (q == 0) atomicAdd(&cat[j0 + jl], cp);
    }
    {
        const int dl = t >> 2, q = t & 3;
        short8 pk0, pk1;
#pragma unroll
        for (int i = 0; i < 8; ++i) pk0[i] = f2b(Gs[q * 16 + i][dl]);
#pragma unroll
        for (int i = 0; i < 8; ++i) pk1[i] = f2b(Gs[q * 16 + 8 + i][dl]);
        short* gp = GT + (d0 + dl) * 4096 + j0 + q * 16;
        *reinterpret_cast<short8*>(gp) = pk0;
        *reinterpret_cast<short8*>(gp + 8) = pk1;
    }
}

// ---------------------------------------------------------------- FUSED edge weights + final GEMM, j-split (z=2)
// BM=64, BN=256, BK=64, Ktile=2048 (z=2), 512 threads, grid (256,2) = 512 blocks.
__global__ __launch_bounds__(512, 4) void fused_out_split(
        const unsigned int* __restrict__ Hbits, const float* __restrict__ cat,
        const float* __restrict__ dn, const short* __restrict__ GT,
        float* __restrict__ outP, float* __restrict__ rsP) {
    __shared__ short As[64][72];    // 9.2 KB
    __shared__ short Bs[256][72];   // 36.9 KB
    __shared__ float rsS[64][8];
    const int t = threadIdx.x;
    const int wid = t >> 6, lane = t & 63;
    const int wm = wid >> 2, wn = wid & 3;    // 2 m-groups x 4 n-groups
    const int quad = lane >> 4, l15 = lane & 15;
    const long m0 = (long)blockIdx.x * 64;
    const int z = blockIdx.y;
    const int kbase = z * 2048;
    const int r = t & 63, c8 = t >> 6;        // B-value role: row r, 8-col chunk c8
    const float drow = dn[m0 + r];
    const int bo = (c8 & 3) * 8;

    f32x4 acc[2][4];
#pragma unroll
    for (int i = 0; i < 2; ++i)
#pragma unroll
        for (int j = 0; j < 4; ++j)
#pragma unroll
            for (int x = 0; x < 4; ++x) acc[i][j][x] = 0.f;
    float racc = 0.f;

    short8 gv[4];   // staged GT tile regs
    short8 pkc;     // staged edge-weight bf16 octet
    // prologue: load + compute step 0
    {
        const int kb = kbase;
#pragma unroll
        for (int it = 0; it < 4; ++it) {
            const int cid = t + it * 512;
            const int row = cid >> 3, cc = (cid & 7) * 8;
            gv[it] = *reinterpret_cast<const short8*>(GT + row * 4096 + kb + cc);
        }
        const unsigned int w = Hbits[(m0 + r) * 128 + (kb >> 5) + (c8 >> 2)];
        const f32x4 cv0 = *reinterpret_cast<const f32x4*>(cat + kb + c8 * 8);
        const f32x4 cv1 = *reinterpret_cast<const f32x4*>(cat + kb + c8 * 8 + 4);
#pragma unroll
        for (int k = 0; k < 8; ++k) {
            const float cvk = (k < 4) ? cv0[k & 3] : cv1[k & 3];
            const float s = ((w >> (bo + k)) & 1u) ? satexpf(cvk + drow) : 0.f;
            const short sb = f2b(s);
            pkc[k] = sb;
            racc += b2f(sb);
        }
    }

    for (int kk = 0; kk < 2048; kk += 64) {
        const int kb = kbase + kk;
        // write staged tile for this step
#pragma unroll
        for (int it = 0; it < 4; ++it) {
            const int cid = t + it * 512;
            const int row = cid >> 3, cc = (cid & 7) * 8;
            *reinterpret_cast<short8*>(&Bs[row][cc]) = gv[it];
        }
        *reinterpret_cast<short8*>(&As[r][c8 * 8]) = pkc;
        __syncthreads();

        // prefetch step k+1 (loads fly under the MFMA cluster)
        const bool pf = (kk < 1984);
        unsigned int hw = 0u;
        f32x4 cn0{}, cn1{};
        if (pf) {
            const int kn = kb + 64;
#pragma unroll
            for (int it = 0; it < 4; ++it) {
                const int cid = t + it * 512;
                const int row = cid >> 3, cc = (cid & 7) * 8;
                gv[it] = *reinterpret_cast<const short8*>(GT + row * 4096 + kn + cc);
            }
            hw = Hbits[(m0 + r) * 128 + (kn >> 5) + (c8 >> 2)];
            cn0 = *reinterpret_cast<const f32x4*>(cat + kn + c8 * 8);
            cn1 = *reinterpret_cast<const f32x4*>(cat + kn + c8 * 8 + 4);
        }

#pragma unroll
        for (int ks = 0; ks < 2; ++ks) {
            short8 af[2], bf[4];
#pragma unroll
            for (int i = 0; i < 2; ++i)
                af[i] = *reinterpret_cast<const short8*>(
                        &As[wm * 32 + i * 16 + l15][ks * 32 + quad * 8]);
#pragma unroll
            for (int j = 0; j < 4; ++j)
                bf[j] = *reinterpret_cast<const short8*>(
                        &Bs[wn * 64 + j * 16 + l15][ks * 32 + quad * 8]);
#pragma unroll
            for (int i = 0; i < 2; ++i)
#pragma unroll
                for (int j = 0; j < 4; ++j)
                    acc[i][j] = __builtin_amdgcn_mfma_f32_16x16x32_bf16(
                            af[i], bf[j], acc[i][j], 0, 0, 0);
        }

        // compute next step's edge weights (load results have had MFMA time to land)
        if (pf) {
#pragma unroll
            for (int k = 0; k < 8; ++k) {
                const float cvk = (k < 4) ? cn0[k & 3] : cn1[k & 3];
                const float s = ((hw >> (bo + k)) & 1u) ? satexpf(cvk + drow) : 0.f;
                const short sb = f2b(s);
                pkc[k] = sb;
                racc += b2f(sb);
            }
        }
        __syncthreads();
    }
    rsS[r][c8] = racc;
    __syncthreads();
    if (t < 64) {
        float s = 0.f;
#pragma unroll
        for (int i = 0; i < 8; ++i) s += rsS[t][i];
        rsP[z * 16384 + m0 + t] = s;
    }
    float* op = outP + (long)z * (16384L * 256);
#pragma unroll
    for (int i = 0; i < 2; ++i) {
#pragma unroll
        for (int j = 0; j < 4; ++j) {
            const long gcol = wn * 64 + j * 16 + l15;
#pragma unroll
            for (int x = 0; x < 4; ++x) {
                const long grow = m0 + wm * 32 + i * 16 + quad * 4 + x;
                op[grow * 256 + gcol] = acc[i][j][x];
            }
        }
    }
}

// ---------------------------------------------------------------- combine: out = leaky(sum_z outP / sum_z rsP)  (z=2)
__global__ __launch_bounds__(256) void combine_out(
        const float* __restrict__ outP, const float* __restrict__ rsP,
        float* __restrict__ out) {
    const long i = ((long)blockIdx.x * 256 + threadIdx.x) * 4;  // grid 4096
    const long n = i >> 8;
    f32x4 s = *reinterpret_cast<const f32x4*>(outP + i);
    {
        f32x4 v = *reinterpret_cast<const f32x4*>(outP + (16384L * 256) + i);
#pragma unroll
        for (int k = 0; k < 4; ++k) s[k] += v[k];
    }
    const float rinv = fastrcp(rsP[n] + rsP[16384 + n]);
    f32x4 o;
#pragma unroll
    for (int k = 0; k < 4; ++k) o[k] = leakyf(s[k] * rinv);
    *reinterpret_cast<f32x4*>(out + i) = o;
}

// ---------------------------------------------------------------- launch
extern "C" void kernel_launch(void* const* d_in, const int* in_sizes, int n_in,
                              void* d_out, int out_size, void* d_ws, size_t ws_size,
                              hipStream_t stream) {
    const float* x   = (const float*)d_in[0];
    const float* H   = (const float*)d_in[1];
    const float* w1  = (const float*)d_in[2];
    const float* w2  = (const float*)d_in[3];
    const float* a1  = (const float*)d_in[4];
    const float* a21 = (const float*)d_in[5];
    const float* a22 = (const float*)d_in[6];
    float* out = (float*)d_out;
    char* ws = (char*)d_ws;

    // region0: xw1 fp32 (16.8MB) then C1p fp32 [8][4096][288] (37.75MB) -- sequential reuse
    float* xw1   = (float*)(ws + 0);
    float* C1p   = (float*)(ws + 0);
    char*  yQ    = (char*)(ws + 67108864);                // [576,16384] i8 (9.44MB)
    float* dn    = (float*)(ws + 76546048);               // [16384]
    float* g     = (float*)(ws + 76611584);               // [16384]
    unsigned int* ddmax = (unsigned int*)(ws + 76677120); // [288]
    short* w1Th  = (short*)(ws + 76681216);
    short* w1Tl  = (short*)(ws + 76812288);
    short* w2Th  = (short*)(ws + 76943360);
    short* w2Tl  = (short*)(ws + 77074432);
    float* C1    = (float*)(ws + 77205504);               // [4096,288]
    short* GT    = (short*)(ws + 81924096);               // [256,4096] bf16
    float* cat   = (float*)(ws + 84021248);               // [4096]
    unsigned int* Hbits  = (unsigned int*)(ws + 84037632);// [16384,128] (8MB)
    unsigned int* HbitsT = (unsigned int*)(ws + 92426240);// [4096,512]  (8MB)
    float* outP  = (float*)(ws + 134217728);              // [2][16384,256] (33.6MB)
    float* rsP   = (float*)(ws + 201326592);              // [2][16384]

    transposeH_pack<<<dim3(256, 64), 256, 0, stream>>>(
            H, Hbits, HbitsT, ddmax, cat, w1, w1Th, w1Tl, w2, w2Th, w2Tl);

    gemm_xw1<<<dim3(128, 4), 256, 0, stream>>>(x, w1Th, w1Tl, xw1);
    node_stats1<<<dim3(256), 256, 0, stream>>>(xw1, a1, a22, g, dn, ddmax);
    quantize_y<<<dim3(256), 256, 0, stream>>>(xw1, g, ddmax, yQ);

    gemm_c1_bits<<<dim3(16, 6, 8), 256, 0, stream>>>(HbitsT, yQ, C1p);
    reduce_C1<<<dim3(4608), 256, 0, stream>>>(C1p, ddmax, C1);

    gemm_G<<<dim3(64, 4), 256, 0, stream>>>(C1, w2Th, w2Tl, a21, GT, cat);

    fused_out_split<<<dim3(256, 2), 512, 0, stream>>>(Hbits, cat, dn, GT, outP, rsP);
    combine_out<<<dim3(4096), 256, 0, stream>>>(outP, rsP, out);
}